// Round 7
// baseline (2362.267 us; speedup 1.0000x reference)
//
#include <hip/hip_runtime.h>
#include <hip/hip_bf16.h>
#include <math.h>

// Problem constants: B,N,E,S,A,P,T
#define BG 512
#define NN 65536
#define EE 131072
#define SD 256
#define AD 512
#define PP 2
#define TD 64

typedef __attribute__((ext_vector_type(8))) short sx8;   // 8 bf16 (4 VGPRs)
typedef __attribute__((ext_vector_type(4))) short sx4;
typedef __attribute__((ext_vector_type(4))) float fx4;

__device__ __forceinline__ float bs2f(short s) {
    union { unsigned u; float f; } x; x.u = ((unsigned)(unsigned short)s) << 16; return x.f;
}
__device__ __forceinline__ short f2bs(float f) {
    union { float f; unsigned u; } x; x.f = f;
    unsigned r = x.u + 0x7fffu + ((x.u >> 16) & 1u);   // RNE (finite inputs)
    return (short)(r >> 16);
}
// branch-free fast tanh/sigmoid (v_exp_f32 path, clamped -> no inf/NaN)
__device__ __forceinline__ float fast_tanh(float x) {
    float xc = fminf(fmaxf(x, -15.f), 15.f);
    float e = __expf(2.f * xc);
    return __fdividef(e - 1.f, e + 1.f);
}
__device__ __forceinline__ float fast_sigm(float x) {
    float xc = fminf(fmaxf(x, -30.f), 30.f);
    float e = __expf(-xc);
    return __fdividef(1.f, 1.f + e);
}
__device__ __forceinline__ bool run_flag(const void* runv, int idx) {
    const unsigned char* r8 = (const unsigned char*)runv;
    const int* r32 = (const int*)runv;
    return (r8[idx] != 0) || (r32[idx] != 0);
}

// async global->LDS, 16B per lane; dest = wave-uniform base + lane*16
__device__ __forceinline__ void gload16(const short* g, short* l) {
    __builtin_amdgcn_global_load_lds(
        (const __attribute__((address_space(1))) void*)g,
        (__attribute__((address_space(3))) void*)l, 16, 0, 0);
}

// ---------------------------------------------------------------------------
// 128x128-tile bf16-MFMA GEMM:  C[m,n] = sum_k A[m,k] * W[n,k]  (+bias[n])
// A and W bf16, k-contiguous. global_load_lds staging, DOUBLE-BUFFERED
// (round-5 structure: one __syncthreads per K-step; round-6's 3-buffer
// counted-vmcnt pipeline REVERTED — it cost occupancy 38->30% for no gain).
// __launch_bounds__(256,5): LDS 32KB allows exactly 5 blocks/CU; the old
// bound of 4 was the occupancy limiter in this latency-bound regime.
// LDS XOR-swizzle on staging (pre-swizzled global src + read-side XOR).
// 1-D grid, n-tile fastest + XCD-chunk swizzle (nwg%8==0 at all call sites).
// EPI 0/2 use SWAPPED mfma operands -> lane&15 = row m, regs = 4 consec cols:
// 8B vector gathers/stores (per-instruction coalesced).
//   EPI=0: store bf16 C (+bias)
//   EPI=2: store bf16 tanh(acc + nf[esrc[m]][cn] + nf[edst[m]][cn]) (fused T;
//          esrc/edst hoisted before K-loop = issue-early)
//   EPI=4: (unswapped) paired cols, 16-row interleaved W, ROUTED on nsplit:
//          d=acc[ni]+tb[rc], g=sigm(acc[ni+1]+gb[rc]); store BF16 d*g
// ---------------------------------------------------------------------------
template<int EPI>
__launch_bounds__(256, 5)
__global__ void gemm_bt(const short* __restrict__ Abp, const short* __restrict__ Wp,
                        const float* __restrict__ bias, const float* __restrict__ bias2,
                        short* __restrict__ Cout, short* __restrict__ Fout,
                        short* __restrict__ FoutB,
                        const float* __restrict__ biasB, const float* __restrict__ biasB2,
                        const short* __restrict__ nfp,
                        const int* __restrict__ esrc, const int* __restrict__ edst,
                        int K, int NC, int NT, int nsplit)
{
    __shared__ __align__(16) short sA[2 * 4096];
    __shared__ __align__(16) short sB[2 * 4096];
    const int t = threadIdx.x;
    const int lane = t & 63;
    const int w = t >> 6;

    // XCD-chunk swizzle (m157): blocks sharing an A panel run on one XCD.
    const int nwg = gridDim.x;
    const int q = nwg >> 3;                     // nwg % 8 == 0 at every call site
    const int wg = (blockIdx.x & 7) * q + (blockIdx.x >> 3);
    const int mt = wg / NT;
    const int nt = wg - mt * NT;                // n fastest -> A-panel reuse in L2
    const int m0 = mt * 128;
    const int n0 = nt * 128;

    const int wm = (w >> 1) * 64;
    const int wn = (w & 1) * 64;
    const int lr = lane & 15;
    const int lg = lane >> 4;

    fx4 acc[4][4];
#pragma unroll
    for (int i = 0; i < 4; i++)
#pragma unroll
        for (int j = 0; j < 4; j++) { fx4 z = {0.f, 0.f, 0.f, 0.f}; acc[i][j] = z; }

    // staging: thread t covers row r=t>>2, 16B block cblk (XOR-swizzled source
    // so that physical LDS block (t&3) holds logical block (t&3)^((r>>1)&3)).
    // LDS dest stays linear: byte t*16 within each 64-row half (rule #21).
    const int r = t >> 2;
    const int cblk = (t & 3) ^ ((r >> 1) & 3);
    const short* gA = Abp + (size_t)(m0 + r) * K + cblk * 8;
    const short* gB = Wp + (size_t)(n0 + r) * K + cblk * 8;
    const size_t rowskip = (size_t)64 * K;      // (r+64)>>1 & 3 == r>>1 & 3

    auto STAGE = [&](int b, int kk) {
        gload16(gA + kk,           sA + b * 4096 + w * 512);
        gload16(gA + kk + rowskip, sA + b * 4096 + 2048 + w * 512);
        gload16(gB + kk,           sB + b * 4096 + w * 512);
        gload16(gB + kk + rowskip, sB + b * 4096 + 2048 + w * 512);
    };

    STAGE(0, 0);

    // EPI=2: hoist edge-index loads (issue-early; consumed only in epilogue).
    int es[4], ed[4];
    if (EPI == 2) {
#pragma unroll
        for (int mi = 0; mi < 4; mi++) {
            const int m = m0 + wm + mi * 16 + lr;
            es[mi] = esrc[m]; ed[mi] = edst[m];
        }
    }

    __syncthreads();                            // tile 0 ready
    int buf = 0;
    const int xa = (lr >> 1) & 3;               // read-side XOR row term
    for (int kk = 0; kk < K; kk += 32) {
        if (kk + 32 < K) STAGE(buf ^ 1, kk + 32);   // prefetch next tile
        const short* cA = sA + buf * 4096;
        const short* cB = sB + buf * 4096;
        sx8 af[4], bfr[4];
#pragma unroll
        for (int mi = 0; mi < 4; mi++)
            af[mi] = *(const sx8*)(cA + (wm + mi * 16 + lr) * 32 + (lg ^ xa) * 8);
#pragma unroll
        for (int ni = 0; ni < 4; ni++)
            bfr[ni] = *(const sx8*)(cB + (wn + ni * 16 + lr) * 32 + (lg ^ xa) * 8);
#pragma unroll
        for (int mi = 0; mi < 4; mi++)
#pragma unroll
            for (int ni = 0; ni < 4; ni++) {
                if (EPI == 4)       // normal: col=lane&15 -> n
                    acc[mi][ni] = __builtin_amdgcn_mfma_f32_16x16x32_bf16(
                        af[mi], bfr[ni], acc[mi][ni], 0, 0, 0);
                else                // swapped: col=lane&15 -> m, regs -> 4 consec n
                    acc[mi][ni] = __builtin_amdgcn_mfma_f32_16x16x32_bf16(
                        bfr[ni], af[mi], acc[mi][ni], 0, 0, 0);
            }
        __syncthreads();                        // drains vmcnt (next tile) + lgkm
        buf ^= 1;
    }

    if (EPI == 4) {
        // routed: n0 < nsplit -> Fout/bias/bias2, else FoutB/biasB/biasB2
        const bool useB = (n0 >= nsplit);
        short* fo = useB ? FoutB : Fout;
        const float* tb = useB ? biasB : bias;
        const float* gb = useB ? biasB2 : bias2;
        const int ln0 = useB ? (n0 - nsplit) : n0;
        // D layout: col = lane&15 (n within 16), row = (lane>>4)*4 + reg (m)
#pragma unroll
        for (int mi = 0; mi < 4; mi++) {
#pragma unroll
            for (int rg = 0; rg < 4; rg++) {
                const int m = m0 + wm + mi * 16 + lg * 4 + rg;
#pragma unroll
                for (int ni = 0; ni < 4; ni += 2) {
                    const int rc = (((ln0 + wn + ni * 16) >> 5) << 4) + lr;
                    float dv = acc[mi][ni][rg] + tb[rc];
                    float gv = fast_sigm(acc[mi][ni + 1][rg] + gb[rc]);
                    fo[(size_t)m * 512 + rc] = f2bs(dv * gv);
                }
            }
        }
    } else {
        // swapped D layout: m = m0+wm+mi*16+(lane&15); n = n0+wn+ni*16+lg*4+rg
#pragma unroll
        for (int mi = 0; mi < 4; mi++) {
            const int m = m0 + wm + mi * 16 + lr;
            if (EPI == 2) {
                const short* ps = nfp + (size_t)es[mi] * NC + n0;
                const short* pd = nfp + (size_t)ed[mi] * NC + n0;
                short* co = Cout + (size_t)m * NC + n0;
#pragma unroll
                for (int ni = 0; ni < 4; ni++) {
                    const int nc = wn + ni * 16 + lg * 4;
                    sx4 a4 = *(const sx4*)(ps + nc);
                    sx4 b4 = *(const sx4*)(pd + nc);
                    sx4 o;
#pragma unroll
                    for (int rg = 0; rg < 4; rg++)
                        o[rg] = f2bs(fast_tanh(acc[mi][ni][rg]
                                               + bs2f(a4[rg]) + bs2f(b4[rg])));
                    *(sx4*)(co + nc) = o;
                }
            } else {                            // EPI == 0
                short* co = Cout + (size_t)m * NC + n0;
#pragma unroll
                for (int ni = 0; ni < 4; ni++) {
                    const int nc = wn + ni * 16 + lg * 4;
                    fx4 vb = {0.f, 0.f, 0.f, 0.f};
                    if (bias) vb = *(const fx4*)(bias + n0 + nc);
                    sx4 o;
#pragma unroll
                    for (int rg = 0; rg < 4; rg++)
                        o[rg] = f2bs(acc[mi][ni][rg] + vb[rg]);
                    *(sx4*)(co + nc) = o;
                }
            }
        }
    }
}

// f32 -> bf16 pre-cast (count divisible by 1024)
__global__ void k_castw(const float* __restrict__ in, short* __restrict__ out)
{
    size_t i = ((size_t)blockIdx.x * 256 + threadIdx.x) * 4;
    fx4 v = *(const fx4*)(in + i);
    sx4 o;
#pragma unroll
    for (int u = 0; u < 4; u++) o[u] = f2bs(v[u]);
    *(sx4*)(out + i) = o;
}

// stacked data/gate weights, 16-row interleave: out row r2 (of 1024):
// pair=r2>>5, kind=(r2>>4)&1, within=r2&15 -> src row pair*16+within of tW/gW
__global__ void k_cast_pair(const float* __restrict__ tW, const float* __restrict__ gW,
                            short* __restrict__ out)
{
    size_t i = ((size_t)blockIdx.x * 256 + threadIdx.x) * 4;   // 1024*256 elems
    const int r2 = (int)(i >> 8);
    const int c = (int)(i & 255);
    const int src = ((r2 >> 5) << 4) | (r2 & 15);
    const float* W = ((r2 >> 4) & 1) ? gW : tW;
    fx4 v = *(const fx4*)(W + (size_t)src * 256 + c);
    sx4 o;
#pragma unroll
    for (int u = 0; u < 4; u++) o[u] = f2bs(v[u]);
    *(sx4*)(out + i) = o;
}

// ---------------- CSR build ----------------
__global__ void k_count2(const int* __restrict__ a, const int* __restrict__ b,
                         int* __restrict__ deg, int n)
{
    int i = blockIdx.x * 256 + threadIdx.x;
    if (i < n) { atomicAdd(&deg[a[i]], 1); atomicAdd(&deg[b[i]], 1); }
}
__global__ void k_count1(const int* __restrict__ a, int* __restrict__ deg, int n)
{
    int i = blockIdx.x * 256 + threadIdx.x;
    if (i < n) atomicAdd(&deg[a[i]], 1);
}
// exclusive scan, single block of 256 threads, n divisible by 256
__global__ void k_scan(const int* __restrict__ deg, int* __restrict__ offs, int n)
{
    __shared__ int part[256];
    const int t = threadIdx.x;
    const int chunk = n >> 8;
    const int base = t * chunk;
    int s = 0;
    for (int i = 0; i < chunk; i++) s += deg[base + i];
    part[t] = s;
    __syncthreads();
    for (int off = 1; off < 256; off <<= 1) {
        int v = (t >= off) ? part[t - off] : 0;
        __syncthreads();
        part[t] += v;
        __syncthreads();
    }
    int run = (t > 0) ? part[t - 1] : 0;
    for (int i = 0; i < chunk; i++) {
        offs[base + i] = run;
        run += deg[base + i];
    }
    if (t == 255) offs[n] = part[255];
}
__global__ void k_fill2(const int* __restrict__ a, const int* __restrict__ b,
                        const int* __restrict__ offs, int* __restrict__ cur,
                        int* __restrict__ elist, int n)
{
    int i = blockIdx.x * 256 + threadIdx.x;
    if (i < n) {
        int p = atomicAdd(&cur[a[i]], 1); elist[offs[a[i]] + p] = i;
        int q = atomicAdd(&cur[b[i]], 1); elist[offs[b[i]] + q] = i;
    }
}
__global__ void k_fill1(const int* __restrict__ own, const int* __restrict__ offs,
                        int* __restrict__ cur, int* __restrict__ nlist, int n)
{
    int i = blockIdx.x * 256 + threadIdx.x;
    if (i < n) {
        int p = atomicAdd(&cur[own[i]], 1); nlist[offs[own[i]] + p] = i;
    }
}

// inputs[n,:] = sum over incident entries of msgs[e,:]  (bf16 in, bf16 out)
__global__ void k_edge_gather(const short* __restrict__ msgs, const int* __restrict__ offs,
                              const int* __restrict__ elist, short* __restrict__ inp)
{
    const int node = blockIdx.x * 4 + (threadIdx.x >> 6);  // 4 waves, 1 node each
    const int c = (threadIdx.x & 63) * 8;
    const int s0 = offs[node], s1 = offs[node + 1];
    float acc[8] = {0.f, 0.f, 0.f, 0.f, 0.f, 0.f, 0.f, 0.f};
    for (int s = s0; s < s1; s++) {
        const int e = elist[s];
        sx8 v = *(const sx8*)(msgs + (size_t)e * 512 + c);
#pragma unroll
        for (int u = 0; u < 8; u++) acc[u] += bs2f(v[u]);
    }
    sx8 o;
#pragma unroll
    for (int u = 0; u < 8; u++) o[u] = f2bs(acc[u]);
    *(sx8*)(inp + (size_t)node * 512 + c) = o;
}

// agg[b,:] = sum over nodes of owner b of gp[n,:]   (bf16 in, f32 accum/out)
__global__ void k_owner_reduce(const short* __restrict__ gp, const int* __restrict__ offsB,
                               const int* __restrict__ nlist, float* __restrict__ agg)
{
    const int b = blockIdx.x, t = threadIdx.x;   // 256 threads, 2 cols each
    const int s0 = offsB[b], s1 = offsB[b + 1];
    float a0 = 0.f, a1 = 0.f;
    for (int s = s0; s < s1; s++) {
        const int n = nlist[s];
        const short* pp = gp + (size_t)n * 512 + t * 2;
        a0 += bs2f(pp[0]); a1 += bs2f(pp[1]);
    }
    agg[(size_t)b * 512 + t * 2] = a0;
    agg[(size_t)b * 512 + t * 2 + 1] = a1;
}

// GRU combine: state kept bf16, updated in place. gates from gi/gh (bf16).
__global__ void k_gru(const short* __restrict__ gi, const short* __restrict__ gh,
                      short* __restrict__ nodes,
                      const int* __restrict__ owner, const void* __restrict__ runv)
{
    const int n = blockIdx.x * 4 + (threadIdx.x >> 6);   // 4 nodes/block
    const int t = threadIdx.x & 63;                      // 64 lanes, 4 cols each
    const bool run = run_flag(runv, owner[n]);
    const size_t gb = (size_t)n * 768 + t * 4;
    sx4 vir = *(const sx4*)(gi + gb);
    sx4 viz = *(const sx4*)(gi + gb + 256);
    sx4 vin = *(const sx4*)(gi + gb + 512);
    sx4 whr = *(const sx4*)(gh + gb);
    sx4 whz = *(const sx4*)(gh + gb + 256);
    sx4 whn = *(const sx4*)(gh + gb + 512);
    const size_t nbase = (size_t)n * 256 + t * 4;
    sx4 old4 = *(const sx4*)(nodes + nbase);
    sx4 outb;
#pragma unroll
    for (int u = 0; u < 4; u++) {
        float old = bs2f(old4[u]);
        float rr = fast_sigm(bs2f(vir[u]) + bs2f(whr[u]));
        float zz = fast_sigm(bs2f(viz[u]) + bs2f(whz[u]));
        float nn = fast_tanh(bs2f(vin[u]) + rr * bs2f(whn[u]));
        float nv = (1.f - zz) * nn + zz * old;
        outb[u] = run ? f2bs(nv) : old4[u];      // !run: bit-identical writeback
    }
    *(sx4*)(nodes + nbase) = outb;
}

// logits[b,:] = aggD[b,:] @ ntd_W.T + ntd_b   (f32)
__global__ void k_logits(const float* __restrict__ agg, const float* __restrict__ Wt,
                         const float* __restrict__ bt, float* __restrict__ logitsF,
                         float* __restrict__ outL)
{
    __shared__ float row[512];
    const int b = blockIdx.x, t = threadIdx.x;
    for (int k = t; k < 512; k += 128) row[k] = agg[(size_t)b * 512 + k];
    __syncthreads();
    if (t < TD + 1) {
        float acc = bt[t];
        const float* wr = Wt + (size_t)t * 512;
        for (int k = 0; k < 512; k++) acc += row[k] * wr[k];
        logitsF[b * (TD + 1) + t] = acc;
        outL[b * (TD + 1) + t] = acc;
    }
}

__global__ void k_loss(const float* __restrict__ logitsF, const int* __restrict__ reft,
                       const void* __restrict__ runv, float* __restrict__ outLoss)
{
    __shared__ float red[512];
    const int b = threadIdx.x;
    const float* lr = logitsF + b * (TD + 1);
    float mx = lr[0];
    for (int k = 1; k < TD + 1; k++) mx = fmaxf(mx, lr[k]);
    float se = 0.f;
    for (int k = 0; k < TD + 1; k++) se += expf(lr[k] - mx);
    const int sel = reft[b] + 1;
    float pe = logf(se) + mx - lr[sel];
    red[b] = run_flag(runv, b) ? pe : 0.f;
    __syncthreads();
    for (int s = 256; s > 0; s >>= 1) {
        if (b < s) red[b] += red[b + s];
        __syncthreads();
    }
    if (b == 0) outLoss[0] = red[0] / (float)BG;
}

__global__ void k_newfeat(const float* __restrict__ aggi, const float* __restrict__ nte,
                          const int* __restrict__ reft, const float* __restrict__ f1W,
                          const float* __restrict__ f1b, const float* __restrict__ f2W,
                          float* __restrict__ outNF)
{
    __shared__ float emb[256];
    __shared__ float ag[512];
    const int b = blockIdx.x, t = threadIdx.x;
    const int rt = reft[b];
    emb[t] = nte[(size_t)rt * 256 + t];
    ag[t] = aggi[(size_t)b * 512 + t];
    ag[t + 256] = aggi[(size_t)b * 512 + 256 + t];
    __syncthreads();
    float acc = f1b[t];
    const float* w1 = f1W + (size_t)t * 256;
    for (int k = 0; k < 256; k++) acc += emb[k] * w1[k];
    const float* w2 = f2W + (size_t)t * 512;
    for (int a = 0; a < 512; a++) acc += ag[a] * w2[a];
    outNF[(size_t)b * 256 + t] = acc;
}

extern "C" void kernel_launch(void* const* d_in, const int* in_sizes, int n_in,
                              void* d_out, int out_size, void* d_ws, size_t ws_size,
                              hipStream_t stream)
{
    (void)in_sizes; (void)n_in; (void)out_size;
    const float* in_nodes = (const float*)d_in[0];
    const float* in_ef    = (const float*)d_in[1];
    const int*   e_src    = (const int*)d_in[2];
    const int*   e_dst    = (const int*)d_in[3];
    const int*   owner    = (const int*)d_in[4];
    const void*  running  = d_in[5];
    const int*   reft     = (const int*)d_in[6];
    const float* dec_tW = (const float*)d_in[7];
    const float* dec_tb = (const float*)d_in[8];
    const float* dec_gW = (const float*)d_in[9];
    const float* dec_gb = (const float*)d_in[10];
    const float* init_tW = (const float*)d_in[11];
    const float* init_tb = (const float*)d_in[12];
    const float* init_gW = (const float*)d_in[13];
    const float* init_gb = (const float*)d_in[14];
    const float* ntdW = (const float*)d_in[15];
    const float* ntdb = (const float*)d_in[16];
    const float* nte  = (const float*)d_in[17];
    const float* f1W  = (const float*)d_in[18];
    const float* f1b  = (const float*)d_in[19];
    const float* f2W  = (const float*)d_in[20];
    const float* mnW  = (const float*)d_in[21];
    const float* mfW  = (const float*)d_in[22];
    const float* ml2W = (const float*)d_in[23];
    const float* ml2b = (const float*)d_in[24];
    const float* Wih  = (const float*)d_in[25];
    const float* Whh  = (const float*)d_in[26];
    const float* bih  = (const float*)d_in[27];
    const float* bhh  = (const float*)d_in[28];

    float* outL    = (float*)d_out;                        // [512,65] f32
    float* outNF   = outL + BG * (TD + 1);                 // [512,256] f32
    float* outLoss = outNF + BG * SD;                      // [1] f32

    size_t off = 0;
    auto take = [&](size_t bytes) -> void* {
        void* p = (char*)d_ws + off;
        off += (bytes + 255) & ~(size_t)255;
        return p;
    };
    short* nodes_bf  = (short*)take((size_t)NN * SD * 2);      // 33 MB bf16 state
    short* ef_bf     = (short*)take((size_t)EE * SD * 2);      // 67 MB bf16 edge feats
    short* bufC      = (short*)take((size_t)NN * 512 * 2);     // nf
    short* bufD      = (short*)take((size_t)EE * 512 * 2);     // T, later gi / gp_ini
    short* bufM      = (short*)take((size_t)EE * 512 * 2);     // msgs, later gh / gp_dec
    short* bufI      = (short*)take((size_t)NN * 512 * 2);     // inputs bf16
    float* aggD      = (float*)take((size_t)BG * AD * 4);
    float* aggI      = (float*)take((size_t)BG * AD * 4);
    float* logitsF   = (float*)take((size_t)BG * (TD + 1) * 4);
    // bf16 weight copies
    short* mnWb  = (short*)take((size_t)PP * 512 * 256 * 2);
    short* mfWb  = (short*)take((size_t)PP * 512 * 256 * 2);
    short* ml2Wb = (short*)take((size_t)PP * 512 * 512 * 2);
    short* WihB  = (short*)take((size_t)PP * 768 * 512 * 2);
    short* WhhB  = (short*)take((size_t)PP * 768 * 256 * 2);
    short* W4agg = (short*)take((size_t)2048 * 256 * 2);       // [dec interleave; init interleave]
    // CSR buffers
    int* deg_e = (int*)take((size_t)NN * 4);
    int* offs_e = (int*)take((size_t)(NN + 1) * 4);
    int* cur_e = (int*)take((size_t)NN * 4);
    int* elist = (int*)take((size_t)2 * EE * 4);
    int* degB = (int*)take((size_t)BG * 4);
    int* offsB = (int*)take((size_t)(BG + 1) * 4);
    int* curB = (int*)take((size_t)BG * 4);
    int* nlist = (int*)take((size_t)NN * 4);
    if (off > ws_size) return;

    short* gi = bufD;            // [N,768] bf16 (T dead by then)
    short* gh = bufM;            // [N,768] bf16 (msgs dead by then)
    short* gpD = bufM;           // [N,512] bf16 (gh dead post-loop)
    short* gpI = bufD;           // [N,512] bf16 (gi dead post-loop)

    // activation pre-casts (enables global_load_lds path everywhere)
    k_castw<<<NN * SD / 1024, 256, 0, stream>>>(in_nodes, nodes_bf);
    k_castw<<<EE * SD / 1024, 256, 0, stream>>>(in_ef, ef_bf);
    // weight pre-casts
    k_castw<<<PP * 512 * 256 / 1024, 256, 0, stream>>>(mnW, mnWb);
    k_castw<<<PP * 512 * 256 / 1024, 256, 0, stream>>>(mfW, mfWb);
    k_castw<<<PP * 512 * 512 / 1024, 256, 0, stream>>>(ml2W, ml2Wb);
    k_castw<<<PP * 768 * 512 / 1024, 256, 0, stream>>>(Wih, WihB);
    k_castw<<<PP * 768 * 256 / 1024, 256, 0, stream>>>(Whh, WhhB);
    k_cast_pair<<<1024 * 256 / 1024, 256, 0, stream>>>(dec_tW, dec_gW, W4agg);
    k_cast_pair<<<1024 * 256 / 1024, 256, 0, stream>>>(init_tW, init_gW,
                                                       W4agg + 1024 * 256);

    // CSR builds (once per launch)
    hipMemsetAsync(deg_e, 0, (size_t)NN * 4, stream);
    hipMemsetAsync(cur_e, 0, (size_t)NN * 4, stream);
    hipMemsetAsync(degB, 0, (size_t)BG * 4, stream);
    hipMemsetAsync(curB, 0, (size_t)BG * 4, stream);
    k_count2<<<(EE + 255) / 256, 256, 0, stream>>>(e_src, e_dst, deg_e, EE);
    k_scan<<<1, 256, 0, stream>>>(deg_e, offs_e, NN);
    k_fill2<<<(EE + 255) / 256, 256, 0, stream>>>(e_src, e_dst, offs_e, cur_e, elist, EE);
    k_count1<<<(NN + 255) / 256, 256, 0, stream>>>(owner, degB, NN);
    k_scan<<<1, 256, 0, stream>>>(degB, offsB, BG);
    k_fill1<<<(NN + 255) / 256, 256, 0, stream>>>(owner, offsB, curB, nlist, NN);

    for (int p = 0; p < PP; p++) {
        // nf = nodes @ mn_W.T            [N,512] bf16
        gemm_bt<0><<<NN / 128 * 4, 256, 0, stream>>>(
            nodes_bf, mnWb + (size_t)p * 512 * 256, nullptr, nullptr, bufC,
            nullptr, nullptr, nullptr, nullptr, nullptr, nullptr, nullptr,
            256, 512, 4, 0);
        // T = tanh(nf[src]+nf[dst] + ef@mf_W.T)   [E,512] bf16 (fused epilogue)
        gemm_bt<2><<<EE / 128 * 4, 256, 0, stream>>>(
            ef_bf, mfWb + (size_t)p * 512 * 256, nullptr, nullptr, bufD,
            nullptr, nullptr, nullptr, nullptr, bufC, e_src, e_dst,
            256, 512, 4, 0);
        // msgs = T @ ml2.T + ml2_b       [E,512] bf16
        gemm_bt<0><<<EE / 128 * 4, 256, 0, stream>>>(
            bufD, ml2Wb + (size_t)p * 512 * 512, ml2b + (size_t)p * 512, nullptr,
            bufM, nullptr, nullptr, nullptr, nullptr, nullptr, nullptr, nullptr,
            512, 512, 4, 0);
        // inputs[n] = sum of msgs over incident edges (CSR gather)
        k_edge_gather<<<NN / 4, 256, 0, stream>>>(bufM, offs_e, elist, bufI);
        // gi = inputs @ Wih.T + bih      [N,768] bf16 (into bufD; T dead)
        gemm_bt<0><<<NN / 128 * 6, 256, 0, stream>>>(
            bufI, WihB + (size_t)p * 768 * 512, bih + (size_t)p * 768, nullptr,
            gi, nullptr, nullptr, nullptr, nullptr, nullptr, nullptr, nullptr,
            512, 768, 6, 0);
        // gh = nodes @ Whh.T + bhh       [N,768] bf16 (into bufM; msgs dead)
        gemm_bt<0><<<NN / 128 * 6, 256, 0, stream>>>(
            nodes_bf, WhhB + (size_t)p * 768 * 256, bhh + (size_t)p * 768, nullptr,
            gh, nullptr, nullptr, nullptr, nullptr, nullptr, nullptr, nullptr,
            256, 768, 6, 0);
        // GRU combine -> nodes_bf (in place, bf16 state)
        k_gru<<<NN / 4, 256, 0, stream>>>(gi, gh, nodes_bf, owner, running);
    }

    // both aggregators in ONE routed GEMM (NC=2048: cols<1024 dec, >=1024 init)
    gemm_bt<4><<<NN / 128 * 16, 256, 0, stream>>>(
        nodes_bf, W4agg, dec_tb, dec_gb, nullptr, gpD, gpI,
        init_tb, init_gb, nullptr, nullptr, nullptr,
        256, 2048, 16, 1024);
    k_owner_reduce<<<BG, 256, 0, stream>>>(gpD, offsB, nlist, aggD);
    k_owner_reduce<<<BG, 256, 0, stream>>>(gpI, offsB, nlist, aggI);

    k_logits<<<BG, 128, 0, stream>>>(aggD, ntdW, ntdb, logitsF, outL);
    k_loss<<<1, 512, 0, stream>>>(logitsF, reft, running, outLoss);
    k_newfeat<<<BG, 256, 0, stream>>>(aggI, nte, reft, f1W, f1b, f2W, outNF);
}

// Round 8
// 1869.554 us; speedup vs baseline: 1.2635x; 1.2635x over previous
//
#include <hip/hip_runtime.h>
#include <hip/hip_bf16.h>
#include <math.h>

// Problem constants: B,N,E,S,A,P,T
#define BG 512
#define NN 65536
#define EE 131072
#define SD 256
#define AD 512
#define PP 2
#define TD 64

typedef __attribute__((ext_vector_type(8))) short sx8;   // 8 bf16 (4 VGPRs)
typedef __attribute__((ext_vector_type(4))) short sx4;
typedef __attribute__((ext_vector_type(4))) float fx4;

__device__ __forceinline__ float bs2f(short s) {
    union { unsigned u; float f; } x; x.u = ((unsigned)(unsigned short)s) << 16; return x.f;
}
__device__ __forceinline__ short f2bs(float f) {
    union { float f; unsigned u; } x; x.f = f;
    unsigned r = x.u + 0x7fffu + ((x.u >> 16) & 1u);   // RNE (finite inputs)
    return (short)(r >> 16);
}
// branch-free fast tanh/sigmoid (v_exp_f32 path, clamped -> no inf/NaN)
__device__ __forceinline__ float fast_tanh(float x) {
    float xc = fminf(fmaxf(x, -15.f), 15.f);
    float e = __expf(2.f * xc);
    return __fdividef(e - 1.f, e + 1.f);
}
__device__ __forceinline__ float fast_sigm(float x) {
    float xc = fminf(fmaxf(x, -30.f), 30.f);
    float e = __expf(-xc);
    return __fdividef(1.f, 1.f + e);
}
__device__ __forceinline__ bool run_flag(const void* runv, int idx) {
    const unsigned char* r8 = (const unsigned char*)runv;
    const int* r32 = (const int*)runv;
    return (r8[idx] != 0) || (r32[idx] != 0);
}

// async global->LDS, 16B per lane; dest = wave-uniform base + lane*16
__device__ __forceinline__ void gload16(const short* g, short* l) {
    __builtin_amdgcn_global_load_lds(
        (const __attribute__((address_space(1))) void*)g,
        (__attribute__((address_space(3))) void*)l, 16, 0, 0);
}

// ---------------------------------------------------------------------------
// 128x128-tile bf16-MFMA GEMM:  C[m,n] = sum_k A[m,k] * W[n,k]  (+bias[n])
// A and W bf16, k-contiguous. global_load_lds staging, DOUBLE-BUFFERED
// (round-5 structure: one __syncthreads per K-step).
// __launch_bounds__(256,4): bound=5 FORCES REGISTER SPILL — unified VGPR+AGPR
// file needs ~124 regs/wave (64 AGPR acc + ~60 VGPR); budget at 5 waves/EU is
// ~102 -> accumulators spill to scratch (round 7: WRITE 138->359MB, +25% dur).
// LDS XOR-swizzle on staging (pre-swizzled global src + read-side XOR).
// 1-D grid, n-tile fastest + XCD-chunk swizzle (nwg%8==0 at all call sites).
// EPI 0/2 use SWAPPED mfma operands -> lane&15 = row m, regs = 4 consec cols:
// 8B vector gathers/stores (per-instruction coalesced).
//   EPI=0: store bf16 C (+bias)
//   EPI=2: store bf16 tanh(acc + nf[esrc[m]][cn] + nf[edst[m]][cn]) (fused T;
//          esrc/edst hoisted before K-loop = issue-early)
//   EPI=4: (unswapped) paired cols, 16-row interleaved W, ROUTED on nsplit:
//          d=acc[ni]+tb[rc], g=sigm(acc[ni+1]+gb[rc]); store BF16 d*g
// ---------------------------------------------------------------------------
template<int EPI>
__launch_bounds__(256, 4)
__global__ void gemm_bt(const short* __restrict__ Abp, const short* __restrict__ Wp,
                        const float* __restrict__ bias, const float* __restrict__ bias2,
                        short* __restrict__ Cout, short* __restrict__ Fout,
                        short* __restrict__ FoutB,
                        const float* __restrict__ biasB, const float* __restrict__ biasB2,
                        const short* __restrict__ nfp,
                        const int* __restrict__ esrc, const int* __restrict__ edst,
                        int K, int NC, int NT, int nsplit)
{
    __shared__ __align__(16) short sA[2 * 4096];
    __shared__ __align__(16) short sB[2 * 4096];
    const int t = threadIdx.x;
    const int lane = t & 63;
    const int w = t >> 6;

    // XCD-chunk swizzle (m157): blocks sharing an A panel run on one XCD.
    const int nwg = gridDim.x;
    const int q = nwg >> 3;                     // nwg % 8 == 0 at every call site
    const int wg = (blockIdx.x & 7) * q + (blockIdx.x >> 3);
    const int mt = wg / NT;
    const int nt = wg - mt * NT;                // n fastest -> A-panel reuse in L2
    const int m0 = mt * 128;
    const int n0 = nt * 128;

    const int wm = (w >> 1) * 64;
    const int wn = (w & 1) * 64;
    const int lr = lane & 15;
    const int lg = lane >> 4;

    fx4 acc[4][4];
#pragma unroll
    for (int i = 0; i < 4; i++)
#pragma unroll
        for (int j = 0; j < 4; j++) { fx4 z = {0.f, 0.f, 0.f, 0.f}; acc[i][j] = z; }

    // staging: thread t covers row r=t>>2, 16B block cblk (XOR-swizzled source
    // so that physical LDS block (t&3) holds logical block (t&3)^((r>>1)&3)).
    // LDS dest stays linear: byte t*16 within each 64-row half (rule #21).
    const int r = t >> 2;
    const int cblk = (t & 3) ^ ((r >> 1) & 3);
    const short* gA = Abp + (size_t)(m0 + r) * K + cblk * 8;
    const short* gB = Wp + (size_t)(n0 + r) * K + cblk * 8;
    const size_t rowskip = (size_t)64 * K;      // (r+64)>>1 & 3 == r>>1 & 3

    auto STAGE = [&](int b, int kk) {
        gload16(gA + kk,           sA + b * 4096 + w * 512);
        gload16(gA + kk + rowskip, sA + b * 4096 + 2048 + w * 512);
        gload16(gB + kk,           sB + b * 4096 + w * 512);
        gload16(gB + kk + rowskip, sB + b * 4096 + 2048 + w * 512);
    };

    STAGE(0, 0);

    // EPI=2: hoist edge-index loads (issue-early; consumed only in epilogue).
    int es[4], ed[4];
    if (EPI == 2) {
#pragma unroll
        for (int mi = 0; mi < 4; mi++) {
            const int m = m0 + wm + mi * 16 + lr;
            es[mi] = esrc[m]; ed[mi] = edst[m];
        }
    }

    __syncthreads();                            // tile 0 ready
    int buf = 0;
    const int xa = (lr >> 1) & 3;               // read-side XOR row term
    for (int kk = 0; kk < K; kk += 32) {
        if (kk + 32 < K) STAGE(buf ^ 1, kk + 32);   // prefetch next tile
        const short* cA = sA + buf * 4096;
        const short* cB = sB + buf * 4096;
        sx8 af[4], bfr[4];
#pragma unroll
        for (int mi = 0; mi < 4; mi++)
            af[mi] = *(const sx8*)(cA + (wm + mi * 16 + lr) * 32 + (lg ^ xa) * 8);
#pragma unroll
        for (int ni = 0; ni < 4; ni++)
            bfr[ni] = *(const sx8*)(cB + (wn + ni * 16 + lr) * 32 + (lg ^ xa) * 8);
#pragma unroll
        for (int mi = 0; mi < 4; mi++)
#pragma unroll
            for (int ni = 0; ni < 4; ni++) {
                if (EPI == 4)       // normal: col=lane&15 -> n
                    acc[mi][ni] = __builtin_amdgcn_mfma_f32_16x16x32_bf16(
                        af[mi], bfr[ni], acc[mi][ni], 0, 0, 0);
                else                // swapped: col=lane&15 -> m, regs -> 4 consec n
                    acc[mi][ni] = __builtin_amdgcn_mfma_f32_16x16x32_bf16(
                        bfr[ni], af[mi], acc[mi][ni], 0, 0, 0);
            }
        __syncthreads();                        // drains vmcnt (next tile) + lgkm
        buf ^= 1;
    }

    if (EPI == 4) {
        // routed: n0 < nsplit -> Fout/bias/bias2, else FoutB/biasB/biasB2
        const bool useB = (n0 >= nsplit);
        short* fo = useB ? FoutB : Fout;
        const float* tb = useB ? biasB : bias;
        const float* gb = useB ? biasB2 : bias2;
        const int ln0 = useB ? (n0 - nsplit) : n0;
        // D layout: col = lane&15 (n within 16), row = (lane>>4)*4 + reg (m)
#pragma unroll
        for (int mi = 0; mi < 4; mi++) {
#pragma unroll
            for (int rg = 0; rg < 4; rg++) {
                const int m = m0 + wm + mi * 16 + lg * 4 + rg;
#pragma unroll
                for (int ni = 0; ni < 4; ni += 2) {
                    const int rc = (((ln0 + wn + ni * 16) >> 5) << 4) + lr;
                    float dv = acc[mi][ni][rg] + tb[rc];
                    float gv = fast_sigm(acc[mi][ni + 1][rg] + gb[rc]);
                    fo[(size_t)m * 512 + rc] = f2bs(dv * gv);
                }
            }
        }
    } else {
        // swapped D layout: m = m0+wm+mi*16+(lane&15); n = n0+wn+ni*16+lg*4+rg
#pragma unroll
        for (int mi = 0; mi < 4; mi++) {
            const int m = m0 + wm + mi * 16 + lr;
            if (EPI == 2) {
                const short* ps = nfp + (size_t)es[mi] * NC + n0;
                const short* pd = nfp + (size_t)ed[mi] * NC + n0;
                short* co = Cout + (size_t)m * NC + n0;
#pragma unroll
                for (int ni = 0; ni < 4; ni++) {
                    const int nc = wn + ni * 16 + lg * 4;
                    sx4 a4 = *(const sx4*)(ps + nc);
                    sx4 b4 = *(const sx4*)(pd + nc);
                    sx4 o;
#pragma unroll
                    for (int rg = 0; rg < 4; rg++)
                        o[rg] = f2bs(fast_tanh(acc[mi][ni][rg]
                                               + bs2f(a4[rg]) + bs2f(b4[rg])));
                    *(sx4*)(co + nc) = o;
                }
            } else {                            // EPI == 0
                short* co = Cout + (size_t)m * NC + n0;
#pragma unroll
                for (int ni = 0; ni < 4; ni++) {
                    const int nc = wn + ni * 16 + lg * 4;
                    fx4 vb = {0.f, 0.f, 0.f, 0.f};
                    if (bias) vb = *(const fx4*)(bias + n0 + nc);
                    sx4 o;
#pragma unroll
                    for (int rg = 0; rg < 4; rg++)
                        o[rg] = f2bs(acc[mi][ni][rg] + vb[rg]);
                    *(sx4*)(co + nc) = o;
                }
            }
        }
    }
}

// f32 -> bf16 pre-cast (count divisible by 1024)
__global__ void k_castw(const float* __restrict__ in, short* __restrict__ out)
{
    size_t i = ((size_t)blockIdx.x * 256 + threadIdx.x) * 4;
    fx4 v = *(const fx4*)(in + i);
    sx4 o;
#pragma unroll
    for (int u = 0; u < 4; u++) o[u] = f2bs(v[u]);
    *(sx4*)(out + i) = o;
}

// stacked data/gate weights, 16-row interleave: out row r2 (of 1024):
// pair=r2>>5, kind=(r2>>4)&1, within=r2&15 -> src row pair*16+within of tW/gW
__global__ void k_cast_pair(const float* __restrict__ tW, const float* __restrict__ gW,
                            short* __restrict__ out)
{
    size_t i = ((size_t)blockIdx.x * 256 + threadIdx.x) * 4;   // 1024*256 elems
    const int r2 = (int)(i >> 8);
    const int c = (int)(i & 255);
    const int src = ((r2 >> 5) << 4) | (r2 & 15);
    const float* W = ((r2 >> 4) & 1) ? gW : tW;
    fx4 v = *(const fx4*)(W + (size_t)src * 256 + c);
    sx4 o;
#pragma unroll
    for (int u = 0; u < 4; u++) o[u] = f2bs(v[u]);
    *(sx4*)(out + i) = o;
}

// ---------------- CSR build ----------------
__global__ void k_count2(const int* __restrict__ a, const int* __restrict__ b,
                         int* __restrict__ deg, int n)
{
    int i = blockIdx.x * 256 + threadIdx.x;
    if (i < n) { atomicAdd(&deg[a[i]], 1); atomicAdd(&deg[b[i]], 1); }
}
__global__ void k_count1(const int* __restrict__ a, int* __restrict__ deg, int n)
{
    int i = blockIdx.x * 256 + threadIdx.x;
    if (i < n) atomicAdd(&deg[a[i]], 1);
}
// exclusive scan, single block of 256 threads, n divisible by 256
__global__ void k_scan(const int* __restrict__ deg, int* __restrict__ offs, int n)
{
    __shared__ int part[256];
    const int t = threadIdx.x;
    const int chunk = n >> 8;
    const int base = t * chunk;
    int s = 0;
    for (int i = 0; i < chunk; i++) s += deg[base + i];
    part[t] = s;
    __syncthreads();
    for (int off = 1; off < 256; off <<= 1) {
        int v = (t >= off) ? part[t - off] : 0;
        __syncthreads();
        part[t] += v;
        __syncthreads();
    }
    int run = (t > 0) ? part[t - 1] : 0;
    for (int i = 0; i < chunk; i++) {
        offs[base + i] = run;
        run += deg[base + i];
    }
    if (t == 255) offs[n] = part[255];
}
__global__ void k_fill2(const int* __restrict__ a, const int* __restrict__ b,
                        const int* __restrict__ offs, int* __restrict__ cur,
                        int* __restrict__ elist, int n)
{
    int i = blockIdx.x * 256 + threadIdx.x;
    if (i < n) {
        int p = atomicAdd(&cur[a[i]], 1); elist[offs[a[i]] + p] = i;
        int q = atomicAdd(&cur[b[i]], 1); elist[offs[b[i]] + q] = i;
    }
}
__global__ void k_fill1(const int* __restrict__ own, const int* __restrict__ offs,
                        int* __restrict__ cur, int* __restrict__ nlist, int n)
{
    int i = blockIdx.x * 256 + threadIdx.x;
    if (i < n) {
        int p = atomicAdd(&cur[own[i]], 1); nlist[offs[own[i]] + p] = i;
    }
}

// inputs[n,:] = sum over incident entries of msgs[e,:]  (bf16 in, bf16 out)
__global__ void k_edge_gather(const short* __restrict__ msgs, const int* __restrict__ offs,
                              const int* __restrict__ elist, short* __restrict__ inp)
{
    const int node = blockIdx.x * 4 + (threadIdx.x >> 6);  // 4 waves, 1 node each
    const int c = (threadIdx.x & 63) * 8;
    const int s0 = offs[node], s1 = offs[node + 1];
    float acc[8] = {0.f, 0.f, 0.f, 0.f, 0.f, 0.f, 0.f, 0.f};
    for (int s = s0; s < s1; s++) {
        const int e = elist[s];
        sx8 v = *(const sx8*)(msgs + (size_t)e * 512 + c);
#pragma unroll
        for (int u = 0; u < 8; u++) acc[u] += bs2f(v[u]);
    }
    sx8 o;
#pragma unroll
    for (int u = 0; u < 8; u++) o[u] = f2bs(acc[u]);
    *(sx8*)(inp + (size_t)node * 512 + c) = o;
}

// agg[b,:] = sum over nodes of owner b of gp[n,:]   (bf16 in, f32 accum/out)
__global__ void k_owner_reduce(const short* __restrict__ gp, const int* __restrict__ offsB,
                               const int* __restrict__ nlist, float* __restrict__ agg)
{
    const int b = blockIdx.x, t = threadIdx.x;   // 256 threads, 2 cols each
    const int s0 = offsB[b], s1 = offsB[b + 1];
    float a0 = 0.f, a1 = 0.f;
    for (int s = s0; s < s1; s++) {
        const int n = nlist[s];
        const short* pp = gp + (size_t)n * 512 + t * 2;
        a0 += bs2f(pp[0]); a1 += bs2f(pp[1]);
    }
    agg[(size_t)b * 512 + t * 2] = a0;
    agg[(size_t)b * 512 + t * 2 + 1] = a1;
}

// GRU combine: state kept bf16, updated in place. gates from gi/gh (bf16).
__global__ void k_gru(const short* __restrict__ gi, const short* __restrict__ gh,
                      short* __restrict__ nodes,
                      const int* __restrict__ owner, const void* __restrict__ runv)
{
    const int n = blockIdx.x * 4 + (threadIdx.x >> 6);   // 4 nodes/block
    const int t = threadIdx.x & 63;                      // 64 lanes, 4 cols each
    const bool run = run_flag(runv, owner[n]);
    const size_t gb = (size_t)n * 768 + t * 4;
    sx4 vir = *(const sx4*)(gi + gb);
    sx4 viz = *(const sx4*)(gi + gb + 256);
    sx4 vin = *(const sx4*)(gi + gb + 512);
    sx4 whr = *(const sx4*)(gh + gb);
    sx4 whz = *(const sx4*)(gh + gb + 256);
    sx4 whn = *(const sx4*)(gh + gb + 512);
    const size_t nbase = (size_t)n * 256 + t * 4;
    sx4 old4 = *(const sx4*)(nodes + nbase);
    sx4 outb;
#pragma unroll
    for (int u = 0; u < 4; u++) {
        float old = bs2f(old4[u]);
        float rr = fast_sigm(bs2f(vir[u]) + bs2f(whr[u]));
        float zz = fast_sigm(bs2f(viz[u]) + bs2f(whz[u]));
        float nn = fast_tanh(bs2f(vin[u]) + rr * bs2f(whn[u]));
        float nv = (1.f - zz) * nn + zz * old;
        outb[u] = run ? f2bs(nv) : old4[u];      // !run: bit-identical writeback
    }
    *(sx4*)(nodes + nbase) = outb;
}

// logits[b,:] = aggD[b,:] @ ntd_W.T + ntd_b   (f32)
__global__ void k_logits(const float* __restrict__ agg, const float* __restrict__ Wt,
                         const float* __restrict__ bt, float* __restrict__ logitsF,
                         float* __restrict__ outL)
{
    __shared__ float row[512];
    const int b = blockIdx.x, t = threadIdx.x;
    for (int k = t; k < 512; k += 128) row[k] = agg[(size_t)b * 512 + k];
    __syncthreads();
    if (t < TD + 1) {
        float acc = bt[t];
        const float* wr = Wt + (size_t)t * 512;
        for (int k = 0; k < 512; k++) acc += row[k] * wr[k];
        logitsF[b * (TD + 1) + t] = acc;
        outL[b * (TD + 1) + t] = acc;
    }
}

__global__ void k_loss(const float* __restrict__ logitsF, const int* __restrict__ reft,
                       const void* __restrict__ runv, float* __restrict__ outLoss)
{
    __shared__ float red[512];
    const int b = threadIdx.x;
    const float* lr = logitsF + b * (TD + 1);
    float mx = lr[0];
    for (int k = 1; k < TD + 1; k++) mx = fmaxf(mx, lr[k]);
    float se = 0.f;
    for (int k = 0; k < TD + 1; k++) se += expf(lr[k] - mx);
    const int sel = reft[b] + 1;
    float pe = logf(se) + mx - lr[sel];
    red[b] = run_flag(runv, b) ? pe : 0.f;
    __syncthreads();
    for (int s = 256; s > 0; s >>= 1) {
        if (b < s) red[b] += red[b + s];
        __syncthreads();
    }
    if (b == 0) outLoss[0] = red[0] / (float)BG;
}

__global__ void k_newfeat(const float* __restrict__ aggi, const float* __restrict__ nte,
                          const int* __restrict__ reft, const float* __restrict__ f1W,
                          const float* __restrict__ f1b, const float* __restrict__ f2W,
                          float* __restrict__ outNF)
{
    __shared__ float emb[256];
    __shared__ float ag[512];
    const int b = blockIdx.x, t = threadIdx.x;
    const int rt = reft[b];
    emb[t] = nte[(size_t)rt * 256 + t];
    ag[t] = aggi[(size_t)b * 512 + t];
    ag[t + 256] = aggi[(size_t)b * 512 + 256 + t];
    __syncthreads();
    float acc = f1b[t];
    const float* w1 = f1W + (size_t)t * 256;
    for (int k = 0; k < 256; k++) acc += emb[k] * w1[k];
    const float* w2 = f2W + (size_t)t * 512;
    for (int a = 0; a < 512; a++) acc += ag[a] * w2[a];
    outNF[(size_t)b * 256 + t] = acc;
}

extern "C" void kernel_launch(void* const* d_in, const int* in_sizes, int n_in,
                              void* d_out, int out_size, void* d_ws, size_t ws_size,
                              hipStream_t stream)
{
    (void)in_sizes; (void)n_in; (void)out_size;
    const float* in_nodes = (const float*)d_in[0];
    const float* in_ef    = (const float*)d_in[1];
    const int*   e_src    = (const int*)d_in[2];
    const int*   e_dst    = (const int*)d_in[3];
    const int*   owner    = (const int*)d_in[4];
    const void*  running  = d_in[5];
    const int*   reft     = (const int*)d_in[6];
    const float* dec_tW = (const float*)d_in[7];
    const float* dec_tb = (const float*)d_in[8];
    const float* dec_gW = (const float*)d_in[9];
    const float* dec_gb = (const float*)d_in[10];
    const float* init_tW = (const float*)d_in[11];
    const float* init_tb = (const float*)d_in[12];
    const float* init_gW = (const float*)d_in[13];
    const float* init_gb = (const float*)d_in[14];
    const float* ntdW = (const float*)d_in[15];
    const float* ntdb = (const float*)d_in[16];
    const float* nte  = (const float*)d_in[17];
    const float* f1W  = (const float*)d_in[18];
    const float* f1b  = (const float*)d_in[19];
    const float* f2W  = (const float*)d_in[20];
    const float* mnW  = (const float*)d_in[21];
    const float* mfW  = (const float*)d_in[22];
    const float* ml2W = (const float*)d_in[23];
    const float* ml2b = (const float*)d_in[24];
    const float* Wih  = (const float*)d_in[25];
    const float* Whh  = (const float*)d_in[26];
    const float* bih  = (const float*)d_in[27];
    const float* bhh  = (const float*)d_in[28];

    float* outL    = (float*)d_out;                        // [512,65] f32
    float* outNF   = outL + BG * (TD + 1);                 // [512,256] f32
    float* outLoss = outNF + BG * SD;                      // [1] f32

    size_t off = 0;
    auto take = [&](size_t bytes) -> void* {
        void* p = (char*)d_ws + off;
        off += (bytes + 255) & ~(size_t)255;
        return p;
    };
    short* nodes_bf  = (short*)take((size_t)NN * SD * 2);      // 33 MB bf16 state
    short* ef_bf     = (short*)take((size_t)EE * SD * 2);      // 67 MB bf16 edge feats
    short* bufC      = (short*)take((size_t)NN * 512 * 2);     // nf
    short* bufD      = (short*)take((size_t)EE * 512 * 2);     // T, later gi / gp_ini
    short* bufM      = (short*)take((size_t)EE * 512 * 2);     // msgs, later gh / gp_dec
    short* bufI      = (short*)take((size_t)NN * 512 * 2);     // inputs bf16
    float* aggD      = (float*)take((size_t)BG * AD * 4);
    float* aggI      = (float*)take((size_t)BG * AD * 4);
    float* logitsF   = (float*)take((size_t)BG * (TD + 1) * 4);
    // bf16 weight copies
    short* mnWb  = (short*)take((size_t)PP * 512 * 256 * 2);
    short* mfWb  = (short*)take((size_t)PP * 512 * 256 * 2);
    short* ml2Wb = (short*)take((size_t)PP * 512 * 512 * 2);
    short* WihB  = (short*)take((size_t)PP * 768 * 512 * 2);
    short* WhhB  = (short*)take((size_t)PP * 768 * 256 * 2);
    short* W4agg = (short*)take((size_t)2048 * 256 * 2);       // [dec interleave; init interleave]
    // CSR buffers
    int* deg_e = (int*)take((size_t)NN * 4);
    int* offs_e = (int*)take((size_t)(NN + 1) * 4);
    int* cur_e = (int*)take((size_t)NN * 4);
    int* elist = (int*)take((size_t)2 * EE * 4);
    int* degB = (int*)take((size_t)BG * 4);
    int* offsB = (int*)take((size_t)(BG + 1) * 4);
    int* curB = (int*)take((size_t)BG * 4);
    int* nlist = (int*)take((size_t)NN * 4);
    if (off > ws_size) return;

    short* gi = bufD;            // [N,768] bf16 (T dead by then)
    short* gh = bufM;            // [N,768] bf16 (msgs dead by then)
    short* gpD = bufM;           // [N,512] bf16 (gh dead post-loop)
    short* gpI = bufD;           // [N,512] bf16 (gi dead post-loop)

    // activation pre-casts (enables global_load_lds path everywhere)
    k_castw<<<NN * SD / 1024, 256, 0, stream>>>(in_nodes, nodes_bf);
    k_castw<<<EE * SD / 1024, 256, 0, stream>>>(in_ef, ef_bf);
    // weight pre-casts
    k_castw<<<PP * 512 * 256 / 1024, 256, 0, stream>>>(mnW, mnWb);
    k_castw<<<PP * 512 * 256 / 1024, 256, 0, stream>>>(mfW, mfWb);
    k_castw<<<PP * 512 * 512 / 1024, 256, 0, stream>>>(ml2W, ml2Wb);
    k_castw<<<PP * 768 * 512 / 1024, 256, 0, stream>>>(Wih, WihB);
    k_castw<<<PP * 768 * 256 / 1024, 256, 0, stream>>>(Whh, WhhB);
    k_cast_pair<<<1024 * 256 / 1024, 256, 0, stream>>>(dec_tW, dec_gW, W4agg);
    k_cast_pair<<<1024 * 256 / 1024, 256, 0, stream>>>(init_tW, init_gW,
                                                       W4agg + 1024 * 256);

    // CSR builds (once per launch)
    hipMemsetAsync(deg_e, 0, (size_t)NN * 4, stream);
    hipMemsetAsync(cur_e, 0, (size_t)NN * 4, stream);
    hipMemsetAsync(degB, 0, (size_t)BG * 4, stream);
    hipMemsetAsync(curB, 0, (size_t)BG * 4, stream);
    k_count2<<<(EE + 255) / 256, 256, 0, stream>>>(e_src, e_dst, deg_e, EE);
    k_scan<<<1, 256, 0, stream>>>(deg_e, offs_e, NN);
    k_fill2<<<(EE + 255) / 256, 256, 0, stream>>>(e_src, e_dst, offs_e, cur_e, elist, EE);
    k_count1<<<(NN + 255) / 256, 256, 0, stream>>>(owner, degB, NN);
    k_scan<<<1, 256, 0, stream>>>(degB, offsB, BG);
    k_fill1<<<(NN + 255) / 256, 256, 0, stream>>>(owner, offsB, curB, nlist, NN);

    for (int p = 0; p < PP; p++) {
        // nf = nodes @ mn_W.T            [N,512] bf16
        gemm_bt<0><<<NN / 128 * 4, 256, 0, stream>>>(
            nodes_bf, mnWb + (size_t)p * 512 * 256, nullptr, nullptr, bufC,
            nullptr, nullptr, nullptr, nullptr, nullptr, nullptr, nullptr,
            256, 512, 4, 0);
        // T = tanh(nf[src]+nf[dst] + ef@mf_W.T)   [E,512] bf16 (fused epilogue)
        gemm_bt<2><<<EE / 128 * 4, 256, 0, stream>>>(
            ef_bf, mfWb + (size_t)p * 512 * 256, nullptr, nullptr, bufD,
            nullptr, nullptr, nullptr, nullptr, bufC, e_src, e_dst,
            256, 512, 4, 0);
        // msgs = T @ ml2.T + ml2_b       [E,512] bf16
        gemm_bt<0><<<EE / 128 * 4, 256, 0, stream>>>(
            bufD, ml2Wb + (size_t)p * 512 * 512, ml2b + (size_t)p * 512, nullptr,
            bufM, nullptr, nullptr, nullptr, nullptr, nullptr, nullptr, nullptr,
            512, 512, 4, 0);
        // inputs[n] = sum of msgs over incident edges (CSR gather)
        k_edge_gather<<<NN / 4, 256, 0, stream>>>(bufM, offs_e, elist, bufI);
        // gi = inputs @ Wih.T + bih      [N,768] bf16 (into bufD; T dead)
        gemm_bt<0><<<NN / 128 * 6, 256, 0, stream>>>(
            bufI, WihB + (size_t)p * 768 * 512, bih + (size_t)p * 768, nullptr,
            gi, nullptr, nullptr, nullptr, nullptr, nullptr, nullptr, nullptr,
            512, 768, 6, 0);
        // gh = nodes @ Whh.T + bhh       [N,768] bf16 (into bufM; msgs dead)
        gemm_bt<0><<<NN / 128 * 6, 256, 0, stream>>>(
            nodes_bf, WhhB + (size_t)p * 768 * 256, bhh + (size_t)p * 768, nullptr,
            gh, nullptr, nullptr, nullptr, nullptr, nullptr, nullptr, nullptr,
            256, 768, 6, 0);
        // GRU combine -> nodes_bf (in place, bf16 state)
        k_gru<<<NN / 4, 256, 0, stream>>>(gi, gh, nodes_bf, owner, running);
    }

    // both aggregators in ONE routed GEMM (NC=2048: cols<1024 dec, >=1024 init)
    gemm_bt<4><<<NN / 128 * 16, 256, 0, stream>>>(
        nodes_bf, W4agg, dec_tb, dec_gb, nullptr, gpD, gpI,
        init_tb, init_gb, nullptr, nullptr, nullptr,
        256, 2048, 16, 1024);
    k_owner_reduce<<<BG, 256, 0, stream>>>(gpD, offsB, nlist, aggD);
    k_owner_reduce<<<BG, 256, 0, stream>>>(gpI, offsB, nlist, aggI);

    k_logits<<<BG, 128, 0, stream>>>(aggD, ntdW, ntdb, logitsF, outL);
    k_loss<<<1, 512, 0, stream>>>(logitsF, reft, running, outLoss);
    k_newfeat<<<BG, 256, 0, stream>>>(aggI, nte, reft, f1W, f1b, f2W, outNF);
}

// Round 9
// 1820.501 us; speedup vs baseline: 1.2976x; 1.0269x over previous
//
#include <hip/hip_runtime.h>
#include <hip/hip_bf16.h>
#include <math.h>

// Problem constants: B,N,E,S,A,P,T
#define BG 512
#define NN 65536
#define EE 131072
#define SD 256
#define AD 512
#define PP 2
#define TD 64

typedef __attribute__((ext_vector_type(8))) short sx8;   // 8 bf16 (4 VGPRs)
typedef __attribute__((ext_vector_type(4))) short sx4;
typedef __attribute__((ext_vector_type(4))) float fx4;

__device__ __forceinline__ float bs2f(short s) {
    union { unsigned u; float f; } x; x.u = ((unsigned)(unsigned short)s) << 16; return x.f;
}
__device__ __forceinline__ short f2bs(float f) {
    union { float f; unsigned u; } x; x.f = f;
    unsigned r = x.u + 0x7fffu + ((x.u >> 16) & 1u);   // RNE (finite inputs)
    return (short)(r >> 16);
}
// branch-free fast tanh/sigmoid (v_exp_f32 path, clamped -> no inf/NaN)
__device__ __forceinline__ float fast_tanh(float x) {
    float xc = fminf(fmaxf(x, -15.f), 15.f);
    float e = __expf(2.f * xc);
    return __fdividef(e - 1.f, e + 1.f);
}
__device__ __forceinline__ float fast_sigm(float x) {
    float xc = fminf(fmaxf(x, -30.f), 30.f);
    float e = __expf(-xc);
    return __fdividef(1.f, 1.f + e);
}
__device__ __forceinline__ bool run_flag(const void* runv, int idx) {
    const unsigned char* r8 = (const unsigned char*)runv;
    const int* r32 = (const int*)runv;
    return (r8[idx] != 0) || (r32[idx] != 0);
}

// async global->LDS, 16B per lane; dest = wave-uniform base + lane*16
__device__ __forceinline__ void gload16(const short* g, short* l) {
    __builtin_amdgcn_global_load_lds(
        (const __attribute__((address_space(1))) void*)g,
        (__attribute__((address_space(3))) void*)l, 16, 0, 0);
}

// ---------------------------------------------------------------------------
// 128x128-tile bf16-MFMA GEMM:  C[m,n] = sum_k A'[m,k] * W[n,k]  (+bias[n])
// A' is the K-CONCAT of two operands: cols [0,Ksp) from Abp (row stride Ksp),
// cols [Ksp,K) from Abp2 (row stride K-Ksp). Normal GEMMs pass Ksp=K,
// Abp2=Abp (second operand never touched). This implements the nf-fusion:
//   T = tanh([X | ef] @ [mnW | mfW]^T),  X = nodes[src]+nodes[dst]
// removing the separate nf GEMM and its random epilogue gathers.
// A,W bf16 k-contiguous. global_load_lds staging, DOUBLE-BUFFERED (round-5
// structure, one __syncthreads per K-step). __launch_bounds__(256,4): bound=5
// spills MFMA accumulators (unified VGPR+AGPR ~124 regs/wave needed).
// LDS XOR-swizzle on staging (pre-swizzled global src + read-side XOR).
// 1-D grid, n-tile fastest + XCD-chunk swizzle (nwg%8==0 at all call sites).
// EPI 0/1 use SWAPPED mfma operands -> lane&15 = row m, regs = 4 consec cols:
// 8B vector stores (per-instruction coalesced).
//   EPI=0: store bf16 C (+bias)
//   EPI=1: store bf16 tanh(C)             (fused T, no bias)
//   EPI=4: (unswapped) paired cols, 16-row interleaved W, ROUTED on nsplit:
//          d=acc[ni]+tb[rc], g=sigm(acc[ni+1]+gb[rc]); store BF16 d*g
// ---------------------------------------------------------------------------
template<int EPI>
__launch_bounds__(256, 4)
__global__ void gemm_bt(const short* __restrict__ Abp, const short* __restrict__ Abp2,
                        const short* __restrict__ Wp,
                        const float* __restrict__ bias, const float* __restrict__ bias2,
                        short* __restrict__ Cout, short* __restrict__ Fout,
                        short* __restrict__ FoutB,
                        const float* __restrict__ biasB, const float* __restrict__ biasB2,
                        int K, int Ksp, int NC, int NT, int nsplit)
{
    __shared__ __align__(16) short sA[2 * 4096];
    __shared__ __align__(16) short sB[2 * 4096];
    const int t = threadIdx.x;
    const int lane = t & 63;
    const int w = t >> 6;

    // XCD-chunk swizzle (m157): blocks sharing an A panel run on one XCD.
    const int nwg = gridDim.x;
    const int q = nwg >> 3;                     // nwg % 8 == 0 at every call site
    const int wg = (blockIdx.x & 7) * q + (blockIdx.x >> 3);
    const int mt = wg / NT;
    const int nt = wg - mt * NT;                // n fastest -> A-panel reuse in L2
    const int m0 = mt * 128;
    const int n0 = nt * 128;

    const int wm = (w >> 1) * 64;
    const int wn = (w & 1) * 64;
    const int lr = lane & 15;
    const int lg = lane >> 4;

    fx4 acc[4][4];
#pragma unroll
    for (int i = 0; i < 4; i++)
#pragma unroll
        for (int j = 0; j < 4; j++) { fx4 z = {0.f, 0.f, 0.f, 0.f}; acc[i][j] = z; }

    // staging: thread t covers row r=t>>2, 16B block cblk (XOR-swizzled source
    // so that physical LDS block (t&3) holds logical block (t&3)^((r>>1)&3)).
    // LDS dest stays linear: byte t*16 within each 64-row half (rule #21).
    const int r = t >> 2;
    const int cblk = (t & 3) ^ ((r >> 1) & 3);
    const short* gA  = Abp  + (size_t)(m0 + r) * Ksp + cblk * 8;
    const short* gA2 = Abp2 + (size_t)(m0 + r) * (K - Ksp) + cblk * 8;
    const short* gB  = Wp + (size_t)(n0 + r) * K + cblk * 8;
    const size_t rsA  = (size_t)64 * Ksp;
    const size_t rsA2 = (size_t)64 * (K - Ksp);
    const size_t rsB  = (size_t)64 * K;         // (r+64)>>1 & 3 == r>>1 & 3

    auto STAGE = [&](int b, int kk) {
        const short* a0 = (kk < Ksp) ? (gA + kk) : (gA2 + (kk - Ksp));
        const size_t rs = (kk < Ksp) ? rsA : rsA2;
        gload16(a0,            sA + b * 4096 + w * 512);
        gload16(a0 + rs,       sA + b * 4096 + 2048 + w * 512);
        gload16(gB + kk,       sB + b * 4096 + w * 512);
        gload16(gB + kk + rsB, sB + b * 4096 + 2048 + w * 512);
    };

    STAGE(0, 0);
    __syncthreads();                            // tile 0 ready
    int buf = 0;
    const int xa = (lr >> 1) & 3;               // read-side XOR row term
    for (int kk = 0; kk < K; kk += 32) {
        if (kk + 32 < K) STAGE(buf ^ 1, kk + 32);   // prefetch next tile
        const short* cA = sA + buf * 4096;
        const short* cB = sB + buf * 4096;
        sx8 af[4], bfr[4];
#pragma unroll
        for (int mi = 0; mi < 4; mi++)
            af[mi] = *(const sx8*)(cA + (wm + mi * 16 + lr) * 32 + (lg ^ xa) * 8);
#pragma unroll
        for (int ni = 0; ni < 4; ni++)
            bfr[ni] = *(const sx8*)(cB + (wn + ni * 16 + lr) * 32 + (lg ^ xa) * 8);
#pragma unroll
        for (int mi = 0; mi < 4; mi++)
#pragma unroll
            for (int ni = 0; ni < 4; ni++) {
                if (EPI == 4)       // normal: col=lane&15 -> n
                    acc[mi][ni] = __builtin_amdgcn_mfma_f32_16x16x32_bf16(
                        af[mi], bfr[ni], acc[mi][ni], 0, 0, 0);
                else                // swapped: col=lane&15 -> m, regs -> 4 consec n
                    acc[mi][ni] = __builtin_amdgcn_mfma_f32_16x16x32_bf16(
                        bfr[ni], af[mi], acc[mi][ni], 0, 0, 0);
            }
        __syncthreads();                        // drains vmcnt (next tile) + lgkm
        buf ^= 1;
    }

    if (EPI == 4) {
        // routed: n0 < nsplit -> Fout/bias/bias2, else FoutB/biasB/biasB2
        const bool useB = (n0 >= nsplit);
        short* fo = useB ? FoutB : Fout;
        const float* tb = useB ? biasB : bias;
        const float* gb = useB ? biasB2 : bias2;
        const int ln0 = useB ? (n0 - nsplit) : n0;
        // D layout: col = lane&15 (n within 16), row = (lane>>4)*4 + reg (m)
#pragma unroll
        for (int mi = 0; mi < 4; mi++) {
#pragma unroll
            for (int rg = 0; rg < 4; rg++) {
                const int m = m0 + wm + mi * 16 + lg * 4 + rg;
#pragma unroll
                for (int ni = 0; ni < 4; ni += 2) {
                    const int rc = (((ln0 + wn + ni * 16) >> 5) << 4) + lr;
                    float dv = acc[mi][ni][rg] + tb[rc];
                    float gv = fast_sigm(acc[mi][ni + 1][rg] + gb[rc]);
                    fo[(size_t)m * 512 + rc] = f2bs(dv * gv);
                }
            }
        }
    } else {
        // swapped D layout: m = m0+wm+mi*16+(lane&15); n = n0+wn+ni*16+lg*4+rg
#pragma unroll
        for (int mi = 0; mi < 4; mi++) {
            const int m = m0 + wm + mi * 16 + lr;
            short* co = Cout + (size_t)m * NC + n0;
#pragma unroll
            for (int ni = 0; ni < 4; ni++) {
                const int nc = wn + ni * 16 + lg * 4;
                sx4 o;
                if (EPI == 1) {
#pragma unroll
                    for (int rg = 0; rg < 4; rg++)
                        o[rg] = f2bs(fast_tanh(acc[mi][ni][rg]));
                } else {                        // EPI == 0
                    fx4 vb = {0.f, 0.f, 0.f, 0.f};
                    if (bias) vb = *(const fx4*)(bias + n0 + nc);
#pragma unroll
                    for (int rg = 0; rg < 4; rg++)
                        o[rg] = f2bs(acc[mi][ni][rg] + vb[rg]);
                }
                *(sx4*)(co + nc) = o;
            }
        }
    }
}

// X[e,:] = nodes[src[e],:] + nodes[dst[e],:]   (bf16; nodes is L2/L3-resident)
__global__ void k_xadd(const short* __restrict__ nodes, const int* __restrict__ esrc,
                       const int* __restrict__ edst, short* __restrict__ X)
{
    size_t idx = ((size_t)blockIdx.x * 256 + threadIdx.x) * 8;
    const int e = (int)(idx >> 8);              // 256 cols per edge
    const int j = (int)(idx & 255);
    const int s = esrc[e], d = edst[e];
    sx8 a = *(const sx8*)(nodes + (size_t)s * 256 + j);
    sx8 b = *(const sx8*)(nodes + (size_t)d * 256 + j);
    sx8 o;
#pragma unroll
    for (int u = 0; u < 8; u++) o[u] = f2bs(bs2f(a[u]) + bs2f(b[u]));
    *(sx8*)(X + idx) = o;
}

// f32 -> bf16 pre-cast (count divisible by 1024)
__global__ void k_castw(const float* __restrict__ in, short* __restrict__ out)
{
    size_t i = ((size_t)blockIdx.x * 256 + threadIdx.x) * 4;
    fx4 v = *(const fx4*)(in + i);
    sx4 o;
#pragma unroll
    for (int u = 0; u < 4; u++) o[u] = f2bs(v[u]);
    *(sx4*)(out + i) = o;
}

// K-concat weight cast: out[n][k] (512x512): k<256 -> mn[n][k], else mf[n][k-256]
__global__ void k_cast_comb(const float* __restrict__ mn, const float* __restrict__ mf,
                            short* __restrict__ out)
{
    size_t i = ((size_t)blockIdx.x * 256 + threadIdx.x) * 4;   // 512*512 elems
    const int n = (int)(i >> 9);
    const int k = (int)(i & 511);
    const float* W = (k < 256) ? (mn + (size_t)n * 256 + k)
                               : (mf + (size_t)n * 256 + (k - 256));
    fx4 v = *(const fx4*)W;
    sx4 o;
#pragma unroll
    for (int u = 0; u < 4; u++) o[u] = f2bs(v[u]);
    *(sx4*)(out + i) = o;
}

// stacked data/gate weights, 16-row interleave: out row r2 (of 1024):
// pair=r2>>5, kind=(r2>>4)&1, within=r2&15 -> src row pair*16+within of tW/gW
__global__ void k_cast_pair(const float* __restrict__ tW, const float* __restrict__ gW,
                            short* __restrict__ out)
{
    size_t i = ((size_t)blockIdx.x * 256 + threadIdx.x) * 4;   // 1024*256 elems
    const int r2 = (int)(i >> 8);
    const int c = (int)(i & 255);
    const int src = ((r2 >> 5) << 4) | (r2 & 15);
    const float* W = ((r2 >> 4) & 1) ? gW : tW;
    fx4 v = *(const fx4*)(W + (size_t)src * 256 + c);
    sx4 o;
#pragma unroll
    for (int u = 0; u < 4; u++) o[u] = f2bs(v[u]);
    *(sx4*)(out + i) = o;
}

// ---------------- CSR build ----------------
__global__ void k_count2(const int* __restrict__ a, const int* __restrict__ b,
                         int* __restrict__ deg, int n)
{
    int i = blockIdx.x * 256 + threadIdx.x;
    if (i < n) { atomicAdd(&deg[a[i]], 1); atomicAdd(&deg[b[i]], 1); }
}
__global__ void k_count1(const int* __restrict__ a, int* __restrict__ deg, int n)
{
    int i = blockIdx.x * 256 + threadIdx.x;
    if (i < n) atomicAdd(&deg[a[i]], 1);
}
// exclusive scan, single block of 256 threads, n divisible by 256
__global__ void k_scan(const int* __restrict__ deg, int* __restrict__ offs, int n)
{
    __shared__ int part[256];
    const int t = threadIdx.x;
    const int chunk = n >> 8;
    const int base = t * chunk;
    int s = 0;
    for (int i = 0; i < chunk; i++) s += deg[base + i];
    part[t] = s;
    __syncthreads();
    for (int off = 1; off < 256; off <<= 1) {
        int v = (t >= off) ? part[t - off] : 0;
        __syncthreads();
        part[t] += v;
        __syncthreads();
    }
    int run = (t > 0) ? part[t - 1] : 0;
    for (int i = 0; i < chunk; i++) {
        offs[base + i] = run;
        run += deg[base + i];
    }
    if (t == 255) offs[n] = part[255];
}
__global__ void k_fill2(const int* __restrict__ a, const int* __restrict__ b,
                        const int* __restrict__ offs, int* __restrict__ cur,
                        int* __restrict__ elist, int n)
{
    int i = blockIdx.x * 256 + threadIdx.x;
    if (i < n) {
        int p = atomicAdd(&cur[a[i]], 1); elist[offs[a[i]] + p] = i;
        int q = atomicAdd(&cur[b[i]], 1); elist[offs[b[i]] + q] = i;
    }
}
__global__ void k_fill1(const int* __restrict__ own, const int* __restrict__ offs,
                        int* __restrict__ cur, int* __restrict__ nlist, int n)
{
    int i = blockIdx.x * 256 + threadIdx.x;
    if (i < n) {
        int p = atomicAdd(&cur[own[i]], 1); nlist[offs[own[i]] + p] = i;
    }
}

// inputs[n,:] = sum over incident entries of msgs[e,:]  (bf16 in, bf16 out)
__global__ void k_edge_gather(const short* __restrict__ msgs, const int* __restrict__ offs,
                              const int* __restrict__ elist, short* __restrict__ inp)
{
    const int node = blockIdx.x * 4 + (threadIdx.x >> 6);  // 4 waves, 1 node each
    const int c = (threadIdx.x & 63) * 8;
    const int s0 = offs[node], s1 = offs[node + 1];
    float acc[8] = {0.f, 0.f, 0.f, 0.f, 0.f, 0.f, 0.f, 0.f};
    for (int s = s0; s < s1; s++) {
        const int e = elist[s];
        sx8 v = *(const sx8*)(msgs + (size_t)e * 512 + c);
#pragma unroll
        for (int u = 0; u < 8; u++) acc[u] += bs2f(v[u]);
    }
    sx8 o;
#pragma unroll
    for (int u = 0; u < 8; u++) o[u] = f2bs(acc[u]);
    *(sx8*)(inp + (size_t)node * 512 + c) = o;
}

// agg[b,:] = sum over nodes of owner b of gp[n,:]   (bf16 in, f32 accum/out)
__global__ void k_owner_reduce(const short* __restrict__ gp, const int* __restrict__ offsB,
                               const int* __restrict__ nlist, float* __restrict__ agg)
{
    const int b = blockIdx.x, t = threadIdx.x;   // 256 threads, 2 cols each
    const int s0 = offsB[b], s1 = offsB[b + 1];
    float a0 = 0.f, a1 = 0.f;
    for (int s = s0; s < s1; s++) {
        const int n = nlist[s];
        const short* pp = gp + (size_t)n * 512 + t * 2;
        a0 += bs2f(pp[0]); a1 += bs2f(pp[1]);
    }
    agg[(size_t)b * 512 + t * 2] = a0;
    agg[(size_t)b * 512 + t * 2 + 1] = a1;
}

// GRU combine: state kept bf16, updated in place. gates from gi/gh (bf16).
__global__ void k_gru(const short* __restrict__ gi, const short* __restrict__ gh,
                      short* __restrict__ nodes,
                      const int* __restrict__ owner, const void* __restrict__ runv)
{
    const int n = blockIdx.x * 4 + (threadIdx.x >> 6);   // 4 nodes/block
    const int t = threadIdx.x & 63;                      // 64 lanes, 4 cols each
    const bool run = run_flag(runv, owner[n]);
    const size_t gb = (size_t)n * 768 + t * 4;
    sx4 vir = *(const sx4*)(gi + gb);
    sx4 viz = *(const sx4*)(gi + gb + 256);
    sx4 vin = *(const sx4*)(gi + gb + 512);
    sx4 whr = *(const sx4*)(gh + gb);
    sx4 whz = *(const sx4*)(gh + gb + 256);
    sx4 whn = *(const sx4*)(gh + gb + 512);
    const size_t nbase = (size_t)n * 256 + t * 4;
    sx4 old4 = *(const sx4*)(nodes + nbase);
    sx4 outb;
#pragma unroll
    for (int u = 0; u < 4; u++) {
        float old = bs2f(old4[u]);
        float rr = fast_sigm(bs2f(vir[u]) + bs2f(whr[u]));
        float zz = fast_sigm(bs2f(viz[u]) + bs2f(whz[u]));
        float nn = fast_tanh(bs2f(vin[u]) + rr * bs2f(whn[u]));
        float nv = (1.f - zz) * nn + zz * old;
        outb[u] = run ? f2bs(nv) : old4[u];      // !run: bit-identical writeback
    }
    *(sx4*)(nodes + nbase) = outb;
}

// logits[b,:] = aggD[b,:] @ ntd_W.T + ntd_b   (f32)
__global__ void k_logits(const float* __restrict__ agg, const float* __restrict__ Wt,
                         const float* __restrict__ bt, float* __restrict__ logitsF,
                         float* __restrict__ outL)
{
    __shared__ float row[512];
    const int b = blockIdx.x, t = threadIdx.x;
    for (int k = t; k < 512; k += 128) row[k] = agg[(size_t)b * 512 + k];
    __syncthreads();
    if (t < TD + 1) {
        float acc = bt[t];
        const float* wr = Wt + (size_t)t * 512;
        for (int k = 0; k < 512; k++) acc += row[k] * wr[k];
        logitsF[b * (TD + 1) + t] = acc;
        outL[b * (TD + 1) + t] = acc;
    }
}

__global__ void k_loss(const float* __restrict__ logitsF, const int* __restrict__ reft,
                       const void* __restrict__ runv, float* __restrict__ outLoss)
{
    __shared__ float red[512];
    const int b = threadIdx.x;
    const float* lr = logitsF + b * (TD + 1);
    float mx = lr[0];
    for (int k = 1; k < TD + 1; k++) mx = fmaxf(mx, lr[k]);
    float se = 0.f;
    for (int k = 0; k < TD + 1; k++) se += expf(lr[k] - mx);
    const int sel = reft[b] + 1;
    float pe = logf(se) + mx - lr[sel];
    red[b] = run_flag(runv, b) ? pe : 0.f;
    __syncthreads();
    for (int s = 256; s > 0; s >>= 1) {
        if (b < s) red[b] += red[b + s];
        __syncthreads();
    }
    if (b == 0) outLoss[0] = red[0] / (float)BG;
}

__global__ void k_newfeat(const float* __restrict__ aggi, const float* __restrict__ nte,
                          const int* __restrict__ reft, const float* __restrict__ f1W,
                          const float* __restrict__ f1b, const float* __restrict__ f2W,
                          float* __restrict__ outNF)
{
    __shared__ float emb[256];
    __shared__ float ag[512];
    const int b = blockIdx.x, t = threadIdx.x;
    const int rt = reft[b];
    emb[t] = nte[(size_t)rt * 256 + t];
    ag[t] = aggi[(size_t)b * 512 + t];
    ag[t + 256] = aggi[(size_t)b * 512 + 256 + t];
    __syncthreads();
    float acc = f1b[t];
    const float* w1 = f1W + (size_t)t * 256;
    for (int k = 0; k < 256; k++) acc += emb[k] * w1[k];
    const float* w2 = f2W + (size_t)t * 512;
    for (int a = 0; a < 512; a++) acc += ag[a] * w2[a];
    outNF[(size_t)b * 256 + t] = acc;
}

extern "C" void kernel_launch(void* const* d_in, const int* in_sizes, int n_in,
                              void* d_out, int out_size, void* d_ws, size_t ws_size,
                              hipStream_t stream)
{
    (void)in_sizes; (void)n_in; (void)out_size;
    const float* in_nodes = (const float*)d_in[0];
    const float* in_ef    = (const float*)d_in[1];
    const int*   e_src    = (const int*)d_in[2];
    const int*   e_dst    = (const int*)d_in[3];
    const int*   owner    = (const int*)d_in[4];
    const void*  running  = d_in[5];
    const int*   reft     = (const int*)d_in[6];
    const float* dec_tW = (const float*)d_in[7];
    const float* dec_tb = (const float*)d_in[8];
    const float* dec_gW = (const float*)d_in[9];
    const float* dec_gb = (const float*)d_in[10];
    const float* init_tW = (const float*)d_in[11];
    const float* init_tb = (const float*)d_in[12];
    const float* init_gW = (const float*)d_in[13];
    const float* init_gb = (const float*)d_in[14];
    const float* ntdW = (const float*)d_in[15];
    const float* ntdb = (const float*)d_in[16];
    const float* nte  = (const float*)d_in[17];
    const float* f1W  = (const float*)d_in[18];
    const float* f1b  = (const float*)d_in[19];
    const float* f2W  = (const float*)d_in[20];
    const float* mnW  = (const float*)d_in[21];
    const float* mfW  = (const float*)d_in[22];
    const float* ml2W = (const float*)d_in[23];
    const float* ml2b = (const float*)d_in[24];
    const float* Wih  = (const float*)d_in[25];
    const float* Whh  = (const float*)d_in[26];
    const float* bih  = (const float*)d_in[27];
    const float* bhh  = (const float*)d_in[28];

    float* outL    = (float*)d_out;                        // [512,65] f32
    float* outNF   = outL + BG * (TD + 1);                 // [512,256] f32
    float* outLoss = outNF + BG * SD;                      // [1] f32

    size_t off = 0;
    auto take = [&](size_t bytes) -> void* {
        void* p = (char*)d_ws + off;
        off += (bytes + 255) & ~(size_t)255;
        return p;
    };
    short* nodes_bf  = (short*)take((size_t)NN * SD * 2);      // 33 MB bf16 state
    short* ef_bf     = (short*)take((size_t)EE * SD * 2);      // 67 MB bf16 edge feats
    short* bufC      = (short*)take((size_t)EE * SD * 2);      // X = nodes[src]+nodes[dst]
    short* bufD      = (short*)take((size_t)EE * 512 * 2);     // T, later gi / gp_ini
    short* bufM      = (short*)take((size_t)EE * 512 * 2);     // msgs, later gh / gp_dec
    short* bufI      = (short*)take((size_t)NN * 512 * 2);     // inputs bf16
    float* aggD      = (float*)take((size_t)BG * AD * 4);
    float* aggI      = (float*)take((size_t)BG * AD * 4);
    float* logitsF   = (float*)take((size_t)BG * (TD + 1) * 4);
    // bf16 weight copies
    short* WcombB = (short*)take((size_t)PP * 512 * 512 * 2);  // [mnW | mfW] K-concat
    short* ml2Wb = (short*)take((size_t)PP * 512 * 512 * 2);
    short* WihB  = (short*)take((size_t)PP * 768 * 512 * 2);
    short* WhhB  = (short*)take((size_t)PP * 768 * 256 * 2);
    short* W4agg = (short*)take((size_t)2048 * 256 * 2);       // [dec interleave; init interleave]
    // CSR buffers
    int* deg_e = (int*)take((size_t)NN * 4);
    int* offs_e = (int*)take((size_t)(NN + 1) * 4);
    int* cur_e = (int*)take((size_t)NN * 4);
    int* elist = (int*)take((size_t)2 * EE * 4);
    int* degB = (int*)take((size_t)BG * 4);
    int* offsB = (int*)take((size_t)(BG + 1) * 4);
    int* curB = (int*)take((size_t)BG * 4);
    int* nlist = (int*)take((size_t)NN * 4);
    if (off > ws_size) return;

    short* gi = bufD;            // [N,768] bf16 (T dead by then)
    short* gh = bufM;            // [N,768] bf16 (msgs dead by then)
    short* gpD = bufM;           // [N,512] bf16 (gh dead post-loop)
    short* gpI = bufD;           // [N,512] bf16 (gi dead post-loop)

    // activation pre-casts (enables global_load_lds path everywhere)
    k_castw<<<NN * SD / 1024, 256, 0, stream>>>(in_nodes, nodes_bf);
    k_castw<<<EE * SD / 1024, 256, 0, stream>>>(in_ef, ef_bf);
    // weight pre-casts
    for (int p = 0; p < PP; p++)
        k_cast_comb<<<512 * 512 / 1024, 256, 0, stream>>>(
            mnW + (size_t)p * 512 * 256, mfW + (size_t)p * 512 * 256,
            WcombB + (size_t)p * 512 * 512);
    k_castw<<<PP * 512 * 512 / 1024, 256, 0, stream>>>(ml2W, ml2Wb);
    k_castw<<<PP * 768 * 512 / 1024, 256, 0, stream>>>(Wih, WihB);
    k_castw<<<PP * 768 * 256 / 1024, 256, 0, stream>>>(Whh, WhhB);
    k_cast_pair<<<1024 * 256 / 1024, 256, 0, stream>>>(dec_tW, dec_gW, W4agg);
    k_cast_pair<<<1024 * 256 / 1024, 256, 0, stream>>>(init_tW, init_gW,
                                                       W4agg + 1024 * 256);

    // CSR builds (once per launch)
    hipMemsetAsync(deg_e, 0, (size_t)NN * 4, stream);
    hipMemsetAsync(cur_e, 0, (size_t)NN * 4, stream);
    hipMemsetAsync(degB, 0, (size_t)BG * 4, stream);
    hipMemsetAsync(curB, 0, (size_t)BG * 4, stream);
    k_count2<<<(EE + 255) / 256, 256, 0, stream>>>(e_src, e_dst, deg_e, EE);
    k_scan<<<1, 256, 0, stream>>>(deg_e, offs_e, NN);
    k_fill2<<<(EE + 255) / 256, 256, 0, stream>>>(e_src, e_dst, offs_e, cur_e, elist, EE);
    k_count1<<<(NN + 255) / 256, 256, 0, stream>>>(owner, degB, NN);
    k_scan<<<1, 256, 0, stream>>>(degB, offsB, BG);
    k_fill1<<<(NN + 255) / 256, 256, 0, stream>>>(owner, offsB, curB, nlist, NN);

    for (int p = 0; p < PP; p++) {
        // X = nodes[src] + nodes[dst]    [E,256] bf16 (nodes L2/L3-hot)
        k_xadd<<<EE / 8, 256, 0, stream>>>(nodes_bf, e_src, e_dst, bufC);
        // T = tanh([X|ef] @ [mnW|mfW]^T) [E,512] bf16 (K-concat GEMM, K=512)
        gemm_bt<1><<<EE / 128 * 4, 256, 0, stream>>>(
            bufC, ef_bf, WcombB + (size_t)p * 512 * 512, nullptr, nullptr,
            bufD, nullptr, nullptr, nullptr, nullptr,
            512, 256, 512, 4, 0);
        // msgs = T @ ml2.T + ml2_b       [E,512] bf16
        gemm_bt<0><<<EE / 128 * 4, 256, 0, stream>>>(
            bufD, bufD, ml2Wb + (size_t)p * 512 * 512, ml2b + (size_t)p * 512,
            nullptr, bufM, nullptr, nullptr, nullptr, nullptr,
            512, 512, 512, 4, 0);
        // inputs[n] = sum of msgs over incident edges (CSR gather)
        k_edge_gather<<<NN / 4, 256, 0, stream>>>(bufM, offs_e, elist, bufI);
        // gi = inputs @ Wih.T + bih      [N,768] bf16 (into bufD; T dead)
        gemm_bt<0><<<NN / 128 * 6, 256, 0, stream>>>(
            bufI, bufI, WihB + (size_t)p * 768 * 512, bih + (size_t)p * 768,
            nullptr, gi, nullptr, nullptr, nullptr, nullptr,
            512, 512, 768, 6, 0);
        // gh = nodes @ Whh.T + bhh       [N,768] bf16 (into bufM; msgs dead)
        gemm_bt<0><<<NN / 128 * 6, 256, 0, stream>>>(
            nodes_bf, nodes_bf, WhhB + (size_t)p * 768 * 256, bhh + (size_t)p * 768,
            nullptr, gh, nullptr, nullptr, nullptr, nullptr,
            256, 256, 768, 6, 0);
        // GRU combine -> nodes_bf (in place, bf16 state)
        k_gru<<<NN / 4, 256, 0, stream>>>(gi, gh, nodes_bf, owner, running);
    }

    // both aggregators in ONE routed GEMM (NC=2048: cols<1024 dec, >=1024 init)
    gemm_bt<4><<<NN / 128 * 16, 256, 0, stream>>>(
        nodes_bf, nodes_bf, W4agg, dec_tb, dec_gb,
        nullptr, gpD, gpI, init_tb, init_gb,
        256, 256, 2048, 16, 1024);
    k_owner_reduce<<<BG, 256, 0, stream>>>(gpD, offsB, nlist, aggD);
    k_owner_reduce<<<BG, 256, 0, stream>>>(gpI, offsB, nlist, aggI);

    k_logits<<<BG, 128, 0, stream>>>(aggD, ntdW, ntdb, logitsF, outL);
    k_loss<<<1, 512, 0, stream>>>(logitsF, reft, running, outLoss);
    k_newfeat<<<BG, 256, 0, stream>>>(aggI, nte, reft, f1W, f1b, f2W, outNF);
}

// Round 10
// 1659.116 us; speedup vs baseline: 1.4238x; 1.0973x over previous
//
#include <hip/hip_runtime.h>
#include <hip/hip_bf16.h>
#include <math.h>

// Problem constants: B,N,E,S,A,P,T
#define BG 512
#define NN 65536
#define EE 131072
#define SD 256
#define AD 512
#define PP 2
#define TD 64

typedef __attribute__((ext_vector_type(8))) short sx8;   // 8 bf16 (4 VGPRs)
typedef __attribute__((ext_vector_type(4))) short sx4;
typedef __attribute__((ext_vector_type(4))) float fx4;

__device__ __forceinline__ float bs2f(short s) {
    union { unsigned u; float f; } x; x.u = ((unsigned)(unsigned short)s) << 16; return x.f;
}
__device__ __forceinline__ short f2bs(float f) {
    union { float f; unsigned u; } x; x.f = f;
    unsigned r = x.u + 0x7fffu + ((x.u >> 16) & 1u);   // RNE (finite inputs)
    return (short)(r >> 16);
}
// branch-free fast tanh/sigmoid (v_exp_f32 path, clamped -> no inf/NaN)
__device__ __forceinline__ float fast_tanh(float x) {
    float xc = fminf(fmaxf(x, -15.f), 15.f);
    float e = __expf(2.f * xc);
    return __fdividef(e - 1.f, e + 1.f);
}
__device__ __forceinline__ float fast_sigm(float x) {
    float xc = fminf(fmaxf(x, -30.f), 30.f);
    float e = __expf(-xc);
    return __fdividef(1.f, 1.f + e);
}
__device__ __forceinline__ bool run_flag(const void* runv, int idx) {
    const unsigned char* r8 = (const unsigned char*)runv;
    const int* r32 = (const int*)runv;
    return (r8[idx] != 0) || (r32[idx] != 0);
}

// async global->LDS, 16B per lane; dest = wave-uniform base + lane*16
__device__ __forceinline__ void gload16(const short* g, short* l) {
    __builtin_amdgcn_global_load_lds(
        (const __attribute__((address_space(1))) void*)g,
        (__attribute__((address_space(3))) void*)l, 16, 0, 0);
}

// ---------------------------------------------------------------------------
// 128x128-tile bf16-MFMA GEMM:  C[m,n] = sum_k A'[m,k] * W[n,k]  (+bias[n])
// A' is the K-CONCAT of two operands: cols [0,Ksp) from Abp (row stride Ksp),
// cols [Ksp,K) from Abp2 (row stride K-Ksp). Normal GEMMs pass Ksp=K.
// A,W bf16 k-contiguous. global_load_lds staging, DOUBLE-BUFFERED (round-5
// structure, one __syncthreads per K-step). __launch_bounds__(256,4): bound=5
// spills MFMA accumulators (unified VGPR+AGPR ~124 regs/wave needed).
// LDS XOR-swizzle on staging (pre-swizzled global src + read-side XOR).
// 1-D grid, n-tile fastest + XCD-chunk swizzle (nwg%8==0 at all call sites).
// EPI 0/1/3 use SWAPPED mfma operands -> lane&15 = row m, regs = 4 consec
// cols: 8B vector stores (per-instruction coalesced).
//   EPI=0: store bf16 C (+bias)
//   EPI=1: store bf16 tanh(C)             (fused T, no bias)
//   EPI=3: store bf16 C + deg[m]*bias2[n] + bias[n]   (gi with ml2 folded in:
//          gi = U@(Wih@ml2)^T + deg*(Wih@ml2_b) + bih)
//   EPI=4: (unswapped) paired cols, 16-row interleaved W, ROUTED on nsplit:
//          d=acc[ni]+tb[rc], g=sigm(acc[ni+1]+gb[rc]); store BF16 d*g
// ---------------------------------------------------------------------------
template<int EPI>
__launch_bounds__(256, 4)
__global__ void gemm_bt(const short* __restrict__ Abp, const short* __restrict__ Abp2,
                        const short* __restrict__ Wp,
                        const float* __restrict__ bias, const float* __restrict__ bias2,
                        short* __restrict__ Cout, short* __restrict__ Fout,
                        short* __restrict__ FoutB,
                        const float* __restrict__ biasB, const float* __restrict__ biasB2,
                        const int* __restrict__ degp,
                        int K, int Ksp, int NC, int NT, int nsplit)
{
    __shared__ __align__(16) short sA[2 * 4096];
    __shared__ __align__(16) short sB[2 * 4096];
    const int t = threadIdx.x;
    const int lane = t & 63;
    const int w = t >> 6;

    // XCD-chunk swizzle (m157): blocks sharing an A panel run on one XCD.
    const int nwg = gridDim.x;
    const int q = nwg >> 3;                     // nwg % 8 == 0 at every call site
    const int wg = (blockIdx.x & 7) * q + (blockIdx.x >> 3);
    const int mt = wg / NT;
    const int nt = wg - mt * NT;                // n fastest -> A-panel reuse in L2
    const int m0 = mt * 128;
    const int n0 = nt * 128;

    const int wm = (w >> 1) * 64;
    const int wn = (w & 1) * 64;
    const int lr = lane & 15;
    const int lg = lane >> 4;

    fx4 acc[4][4];
#pragma unroll
    for (int i = 0; i < 4; i++)
#pragma unroll
        for (int j = 0; j < 4; j++) { fx4 z = {0.f, 0.f, 0.f, 0.f}; acc[i][j] = z; }

    // staging: thread t covers row r=t>>2, 16B block cblk (XOR-swizzled source
    // so that physical LDS block (t&3) holds logical block (t&3)^((r>>1)&3)).
    // LDS dest stays linear: byte t*16 within each 64-row half (rule #21).
    const int r = t >> 2;
    const int cblk = (t & 3) ^ ((r >> 1) & 3);
    const short* gA  = Abp  + (size_t)(m0 + r) * Ksp + cblk * 8;
    const short* gA2 = Abp2 + (size_t)(m0 + r) * (K - Ksp) + cblk * 8;
    const short* gB  = Wp + (size_t)(n0 + r) * K + cblk * 8;
    const size_t rsA  = (size_t)64 * Ksp;
    const size_t rsA2 = (size_t)64 * (K - Ksp);
    const size_t rsB  = (size_t)64 * K;         // (r+64)>>1 & 3 == r>>1 & 3

    auto STAGE = [&](int b, int kk) {
        const short* a0 = (kk < Ksp) ? (gA + kk) : (gA2 + (kk - Ksp));
        const size_t rs = (kk < Ksp) ? rsA : rsA2;
        gload16(a0,            sA + b * 4096 + w * 512);
        gload16(a0 + rs,       sA + b * 4096 + 2048 + w * 512);
        gload16(gB + kk,       sB + b * 4096 + w * 512);
        gload16(gB + kk + rsB, sB + b * 4096 + 2048 + w * 512);
    };

    STAGE(0, 0);

    // EPI=3: hoist per-row degree loads (issue-early; epilogue-only use).
    float dgv[4];
    if (EPI == 3) {
#pragma unroll
        for (int mi = 0; mi < 4; mi++)
            dgv[mi] = (float)degp[m0 + wm + mi * 16 + lr];
    }

    __syncthreads();                            // tile 0 ready
    int buf = 0;
    const int xa = (lr >> 1) & 3;               // read-side XOR row term
    for (int kk = 0; kk < K; kk += 32) {
        if (kk + 32 < K) STAGE(buf ^ 1, kk + 32);   // prefetch next tile
        const short* cA = sA + buf * 4096;
        const short* cB = sB + buf * 4096;
        sx8 af[4], bfr[4];
#pragma unroll
        for (int mi = 0; mi < 4; mi++)
            af[mi] = *(const sx8*)(cA + (wm + mi * 16 + lr) * 32 + (lg ^ xa) * 8);
#pragma unroll
        for (int ni = 0; ni < 4; ni++)
            bfr[ni] = *(const sx8*)(cB + (wn + ni * 16 + lr) * 32 + (lg ^ xa) * 8);
#pragma unroll
        for (int mi = 0; mi < 4; mi++)
#pragma unroll
            for (int ni = 0; ni < 4; ni++) {
                if (EPI == 4)       // normal: col=lane&15 -> n
                    acc[mi][ni] = __builtin_amdgcn_mfma_f32_16x16x32_bf16(
                        af[mi], bfr[ni], acc[mi][ni], 0, 0, 0);
                else                // swapped: col=lane&15 -> m, regs -> 4 consec n
                    acc[mi][ni] = __builtin_amdgcn_mfma_f32_16x16x32_bf16(
                        bfr[ni], af[mi], acc[mi][ni], 0, 0, 0);
            }
        __syncthreads();                        // drains vmcnt (next tile) + lgkm
        buf ^= 1;
    }

    if (EPI == 4) {
        // routed: n0 < nsplit -> Fout/bias/bias2, else FoutB/biasB/biasB2
        const bool useB = (n0 >= nsplit);
        short* fo = useB ? FoutB : Fout;
        const float* tb = useB ? biasB : bias;
        const float* gb = useB ? biasB2 : bias2;
        const int ln0 = useB ? (n0 - nsplit) : n0;
        // D layout: col = lane&15 (n within 16), row = (lane>>4)*4 + reg (m)
#pragma unroll
        for (int mi = 0; mi < 4; mi++) {
#pragma unroll
            for (int rg = 0; rg < 4; rg++) {
                const int m = m0 + wm + mi * 16 + lg * 4 + rg;
#pragma unroll
                for (int ni = 0; ni < 4; ni += 2) {
                    const int rc = (((ln0 + wn + ni * 16) >> 5) << 4) + lr;
                    float dv = acc[mi][ni][rg] + tb[rc];
                    float gv = fast_sigm(acc[mi][ni + 1][rg] + gb[rc]);
                    fo[(size_t)m * 512 + rc] = f2bs(dv * gv);
                }
            }
        }
    } else {
        // swapped D layout: m = m0+wm+mi*16+(lane&15); n = n0+wn+ni*16+lg*4+rg
#pragma unroll
        for (int mi = 0; mi < 4; mi++) {
            const int m = m0 + wm + mi * 16 + lr;
            short* co = Cout + (size_t)m * NC + n0;
#pragma unroll
            for (int ni = 0; ni < 4; ni++) {
                const int nc = wn + ni * 16 + lg * 4;
                sx4 o;
                if (EPI == 1) {
#pragma unroll
                    for (int rg = 0; rg < 4; rg++)
                        o[rg] = f2bs(fast_tanh(acc[mi][ni][rg]));
                } else if (EPI == 3) {
                    fx4 bv = *(const fx4*)(bias + n0 + nc);
                    fx4 cv = *(const fx4*)(bias2 + n0 + nc);
#pragma unroll
                    for (int rg = 0; rg < 4; rg++)
                        o[rg] = f2bs(acc[mi][ni][rg] + dgv[mi] * cv[rg] + bv[rg]);
                } else {                        // EPI == 0
                    fx4 vb = {0.f, 0.f, 0.f, 0.f};
                    if (bias) vb = *(const fx4*)(bias + n0 + nc);
#pragma unroll
                    for (int rg = 0; rg < 4; rg++)
                        o[rg] = f2bs(acc[mi][ni][rg] + vb[rg]);
                }
                *(sx4*)(co + nc) = o;
            }
        }
    }
}

// X[e,:] = nodes[src[e],:] + nodes[dst[e],:]   (bf16; nodes is L2/L3-resident)
__global__ void k_xadd(const short* __restrict__ nodes, const int* __restrict__ esrc,
                       const int* __restrict__ edst, short* __restrict__ X)
{
    size_t idx = ((size_t)blockIdx.x * 256 + threadIdx.x) * 8;
    const int e = (int)(idx >> 8);              // 256 cols per edge
    const int j = (int)(idx & 255);
    const int s = esrc[e], d = edst[e];
    sx8 a = *(const sx8*)(nodes + (size_t)s * 256 + j);
    sx8 b = *(const sx8*)(nodes + (size_t)d * 256 + j);
    sx8 o;
#pragma unroll
    for (int u = 0; u < 8; u++) o[u] = f2bs(bs2f(a[u]) + bs2f(b[u]));
    *(sx8*)(X + idx) = o;
}

// f32 -> bf16 pre-cast (count divisible by 1024)
__global__ void k_castw(const float* __restrict__ in, short* __restrict__ out)
{
    size_t i = ((size_t)blockIdx.x * 256 + threadIdx.x) * 4;
    fx4 v = *(const fx4*)(in + i);
    sx4 o;
#pragma unroll
    for (int u = 0; u < 4; u++) o[u] = f2bs(v[u]);
    *(sx4*)(out + i) = o;
}

// transpose-cast 512x512: out[k][k2] = bf16(in[k2][k])  (for W-operand layout)
__global__ void k_cast_T(const float* __restrict__ in, short* __restrict__ out)
{
    size_t i = ((size_t)blockIdx.x * 256 + threadIdx.x) * 4;   // 512*512 elems
    const int k = (int)(i >> 9);
    const int k2 = (int)(i & 511);
    sx4 o;
#pragma unroll
    for (int u = 0; u < 4; u++) o[u] = f2bs(in[(size_t)(k2 + u) * 512 + k]);
    *(sx4*)(out + i) = o;
}

// c1[i] = sum_k2 Wih[i][k2] * ml2b[k2]   (i < 768; f32)
__global__ void k_vecfuse(const float* __restrict__ Wih, const float* __restrict__ ml2b,
                          float* __restrict__ c1)
{
    const int i = blockIdx.x * 256 + threadIdx.x;
    if (i >= 768) return;
    const float* wr = Wih + (size_t)i * 512;
    float acc = 0.f;
    for (int k = 0; k < 512; k++) acc += wr[k] * ml2b[k];
    c1[i] = acc;
}

// K-concat weight cast: out[n][k] (512x512): k<256 -> mn[n][k], else mf[n][k-256]
__global__ void k_cast_comb(const float* __restrict__ mn, const float* __restrict__ mf,
                            short* __restrict__ out)
{
    size_t i = ((size_t)blockIdx.x * 256 + threadIdx.x) * 4;   // 512*512 elems
    const int n = (int)(i >> 9);
    const int k = (int)(i & 511);
    const float* W = (k < 256) ? (mn + (size_t)n * 256 + k)
                               : (mf + (size_t)n * 256 + (k - 256));
    fx4 v = *(const fx4*)W;
    sx4 o;
#pragma unroll
    for (int u = 0; u < 4; u++) o[u] = f2bs(v[u]);
    *(sx4*)(out + i) = o;
}

// stacked data/gate weights, 16-row interleave: out row r2 (of 1024):
// pair=r2>>5, kind=(r2>>4)&1, within=r2&15 -> src row pair*16+within of tW/gW
__global__ void k_cast_pair(const float* __restrict__ tW, const float* __restrict__ gW,
                            short* __restrict__ out)
{
    size_t i = ((size_t)blockIdx.x * 256 + threadIdx.x) * 4;   // 1024*256 elems
    const int r2 = (int)(i >> 8);
    const int c = (int)(i & 255);
    const int src = ((r2 >> 5) << 4) | (r2 & 15);
    const float* W = ((r2 >> 4) & 1) ? gW : tW;
    fx4 v = *(const fx4*)(W + (size_t)src * 256 + c);
    sx4 o;
#pragma unroll
    for (int u = 0; u < 4; u++) o[u] = f2bs(v[u]);
    *(sx4*)(out + i) = o;
}

// ---------------- CSR build ----------------
__global__ void k_count2(const int* __restrict__ a, const int* __restrict__ b,
                         int* __restrict__ deg, int n)
{
    int i = blockIdx.x * 256 + threadIdx.x;
    if (i < n) { atomicAdd(&deg[a[i]], 1); atomicAdd(&deg[b[i]], 1); }
}
__global__ void k_count1(const int* __restrict__ a, int* __restrict__ deg, int n)
{
    int i = blockIdx.x * 256 + threadIdx.x;
    if (i < n) atomicAdd(&deg[a[i]], 1);
}
// exclusive scan, single block of 256 threads, n divisible by 256
__global__ void k_scan(const int* __restrict__ deg, int* __restrict__ offs, int n)
{
    __shared__ int part[256];
    const int t = threadIdx.x;
    const int chunk = n >> 8;
    const int base = t * chunk;
    int s = 0;
    for (int i = 0; i < chunk; i++) s += deg[base + i];
    part[t] = s;
    __syncthreads();
    for (int off = 1; off < 256; off <<= 1) {
        int v = (t >= off) ? part[t - off] : 0;
        __syncthreads();
        part[t] += v;
        __syncthreads();
    }
    int run = (t > 0) ? part[t - 1] : 0;
    for (int i = 0; i < chunk; i++) {
        offs[base + i] = run;
        run += deg[base + i];
    }
    if (t == 255) offs[n] = part[255];
}
__global__ void k_fill2(const int* __restrict__ a, const int* __restrict__ b,
                        const int* __restrict__ offs, int* __restrict__ cur,
                        int* __restrict__ elist, int n)
{
    int i = blockIdx.x * 256 + threadIdx.x;
    if (i < n) {
        int p = atomicAdd(&cur[a[i]], 1); elist[offs[a[i]] + p] = i;
        int q = atomicAdd(&cur[b[i]], 1); elist[offs[b[i]] + q] = i;
    }
}
__global__ void k_fill1(const int* __restrict__ own, const int* __restrict__ offs,
                        int* __restrict__ cur, int* __restrict__ nlist, int n)
{
    int i = blockIdx.x * 256 + threadIdx.x;
    if (i < n) {
        int p = atomicAdd(&cur[own[i]], 1); nlist[offs[own[i]] + p] = i;
    }
}

// U[n,:] = sum over incident entries of T[e,:]  (bf16 in, bf16 out)
__global__ void k_edge_gather(const short* __restrict__ msgs, const int* __restrict__ offs,
                              const int* __restrict__ elist, short* __restrict__ inp)
{
    const int node = blockIdx.x * 4 + (threadIdx.x >> 6);  // 4 waves, 1 node each
    const int c = (threadIdx.x & 63) * 8;
    const int s0 = offs[node], s1 = offs[node + 1];
    float acc[8] = {0.f, 0.f, 0.f, 0.f, 0.f, 0.f, 0.f, 0.f};
    for (int s = s0; s < s1; s++) {
        const int e = elist[s];
        sx8 v = *(const sx8*)(msgs + (size_t)e * 512 + c);
#pragma unroll
        for (int u = 0; u < 8; u++) acc[u] += bs2f(v[u]);
    }
    sx8 o;
#pragma unroll
    for (int u = 0; u < 8; u++) o[u] = f2bs(acc[u]);
    *(sx8*)(inp + (size_t)node * 512 + c) = o;
}

// agg[b,:] = sum over nodes of owner b of gp[n,:]   (bf16 in, f32 accum/out)
__global__ void k_owner_reduce(const short* __restrict__ gp, const int* __restrict__ offsB,
                               const int* __restrict__ nlist, float* __restrict__ agg)
{
    const int b = blockIdx.x, t = threadIdx.x;   // 256 threads, 2 cols each
    const int s0 = offsB[b], s1 = offsB[b + 1];
    float a0 = 0.f, a1 = 0.f;
    for (int s = s0; s < s1; s++) {
        const int n = nlist[s];
        const short* pp = gp + (size_t)n * 512 + t * 2;
        a0 += bs2f(pp[0]); a1 += bs2f(pp[1]);
    }
    agg[(size_t)b * 512 + t * 2] = a0;
    agg[(size_t)b * 512 + t * 2 + 1] = a1;
}

// GRU combine: state kept bf16, updated in place. gates from gi/gh (bf16).
__global__ void k_gru(const short* __restrict__ gi, const short* __restrict__ gh,
                      short* __restrict__ nodes,
                      const int* __restrict__ owner, const void* __restrict__ runv)
{
    const int n = blockIdx.x * 4 + (threadIdx.x >> 6);   // 4 nodes/block
    const int t = threadIdx.x & 63;                      // 64 lanes, 4 cols each
    const bool run = run_flag(runv, owner[n]);
    const size_t gb = (size_t)n * 768 + t * 4;
    sx4 vir = *(const sx4*)(gi + gb);
    sx4 viz = *(const sx4*)(gi + gb + 256);
    sx4 vin = *(const sx4*)(gi + gb + 512);
    sx4 whr = *(const sx4*)(gh + gb);
    sx4 whz = *(const sx4*)(gh + gb + 256);
    sx4 whn = *(const sx4*)(gh + gb + 512);
    const size_t nbase = (size_t)n * 256 + t * 4;
    sx4 old4 = *(const sx4*)(nodes + nbase);
    sx4 outb;
#pragma unroll
    for (int u = 0; u < 4; u++) {
        float old = bs2f(old4[u]);
        float rr = fast_sigm(bs2f(vir[u]) + bs2f(whr[u]));
        float zz = fast_sigm(bs2f(viz[u]) + bs2f(whz[u]));
        float nn = fast_tanh(bs2f(vin[u]) + rr * bs2f(whn[u]));
        float nv = (1.f - zz) * nn + zz * old;
        outb[u] = run ? f2bs(nv) : old4[u];      // !run: bit-identical writeback
    }
    *(sx4*)(nodes + nbase) = outb;
}

// logits[b,:] = aggD[b,:] @ ntd_W.T + ntd_b   (f32)
__global__ void k_logits(const float* __restrict__ agg, const float* __restrict__ Wt,
                         const float* __restrict__ bt, float* __restrict__ logitsF,
                         float* __restrict__ outL)
{
    __shared__ float row[512];
    const int b = blockIdx.x, t = threadIdx.x;
    for (int k = t; k < 512; k += 128) row[k] = agg[(size_t)b * 512 + k];
    __syncthreads();
    if (t < TD + 1) {
        float acc = bt[t];
        const float* wr = Wt + (size_t)t * 512;
        for (int k = 0; k < 512; k++) acc += row[k] * wr[k];
        logitsF[b * (TD + 1) + t] = acc;
        outL[b * (TD + 1) + t] = acc;
    }
}

__global__ void k_loss(const float* __restrict__ logitsF, const int* __restrict__ reft,
                       const void* __restrict__ runv, float* __restrict__ outLoss)
{
    __shared__ float red[512];
    const int b = threadIdx.x;
    const float* lr = logitsF + b * (TD + 1);
    float mx = lr[0];
    for (int k = 1; k < TD + 1; k++) mx = fmaxf(mx, lr[k]);
    float se = 0.f;
    for (int k = 0; k < TD + 1; k++) se += expf(lr[k] - mx);
    const int sel = reft[b] + 1;
    float pe = logf(se) + mx - lr[sel];
    red[b] = run_flag(runv, b) ? pe : 0.f;
    __syncthreads();
    for (int s = 256; s > 0; s >>= 1) {
        if (b < s) red[b] += red[b + s];
        __syncthreads();
    }
    if (b == 0) outLoss[0] = red[0] / (float)BG;
}

__global__ void k_newfeat(const float* __restrict__ aggi, const float* __restrict__ nte,
                          const int* __restrict__ reft, const float* __restrict__ f1W,
                          const float* __restrict__ f1b, const float* __restrict__ f2W,
                          float* __restrict__ outNF)
{
    __shared__ float emb[256];
    __shared__ float ag[512];
    const int b = blockIdx.x, t = threadIdx.x;
    const int rt = reft[b];
    emb[t] = nte[(size_t)rt * 256 + t];
    ag[t] = aggi[(size_t)b * 512 + t];
    ag[t + 256] = aggi[(size_t)b * 512 + 256 + t];
    __syncthreads();
    float acc = f1b[t];
    const float* w1 = f1W + (size_t)t * 256;
    for (int k = 0; k < 256; k++) acc += emb[k] * w1[k];
    const float* w2 = f2W + (size_t)t * 512;
    for (int a = 0; a < 512; a++) acc += ag[a] * w2[a];
    outNF[(size_t)b * 256 + t] = acc;
}

extern "C" void kernel_launch(void* const* d_in, const int* in_sizes, int n_in,
                              void* d_out, int out_size, void* d_ws, size_t ws_size,
                              hipStream_t stream)
{
    (void)in_sizes; (void)n_in; (void)out_size;
    const float* in_nodes = (const float*)d_in[0];
    const float* in_ef    = (const float*)d_in[1];
    const int*   e_src    = (const int*)d_in[2];
    const int*   e_dst    = (const int*)d_in[3];
    const int*   owner    = (const int*)d_in[4];
    const void*  running  = d_in[5];
    const int*   reft     = (const int*)d_in[6];
    const float* dec_tW = (const float*)d_in[7];
    const float* dec_tb = (const float*)d_in[8];
    const float* dec_gW = (const float*)d_in[9];
    const float* dec_gb = (const float*)d_in[10];
    const float* init_tW = (const float*)d_in[11];
    const float* init_tb = (const float*)d_in[12];
    const float* init_gW = (const float*)d_in[13];
    const float* init_gb = (const float*)d_in[14];
    const float* ntdW = (const float*)d_in[15];
    const float* ntdb = (const float*)d_in[16];
    const float* nte  = (const float*)d_in[17];
    const float* f1W  = (const float*)d_in[18];
    const float* f1b  = (const float*)d_in[19];
    const float* f2W  = (const float*)d_in[20];
    const float* mnW  = (const float*)d_in[21];
    const float* mfW  = (const float*)d_in[22];
    const float* ml2W = (const float*)d_in[23];
    const float* ml2b = (const float*)d_in[24];
    const float* Wih  = (const float*)d_in[25];
    const float* Whh  = (const float*)d_in[26];
    const float* bih  = (const float*)d_in[27];
    const float* bhh  = (const float*)d_in[28];

    float* outL    = (float*)d_out;                        // [512,65] f32
    float* outNF   = outL + BG * (TD + 1);                 // [512,256] f32
    float* outLoss = outNF + BG * SD;                      // [1] f32

    size_t off = 0;
    auto take = [&](size_t bytes) -> void* {
        void* p = (char*)d_ws + off;
        off += (bytes + 255) & ~(size_t)255;
        return p;
    };
    short* nodes_bf  = (short*)take((size_t)NN * SD * 2);      // 33 MB bf16 state
    short* ef_bf     = (short*)take((size_t)EE * SD * 2);      // 67 MB bf16 edge feats
    short* bufC      = (short*)take((size_t)EE * SD * 2);      // X = nodes[src]+nodes[dst]
    short* bufD      = (short*)take((size_t)EE * 512 * 2);     // T, later gi / gp_ini
    short* bufM      = (short*)take((size_t)EE * 512 * 2);     // gh / gp_dec
    short* bufI      = (short*)take((size_t)NN * 512 * 2);     // U = sum of T
    float* aggD      = (float*)take((size_t)BG * AD * 4);
    float* aggI      = (float*)take((size_t)BG * AD * 4);
    float* logitsF   = (float*)take((size_t)BG * (TD + 1) * 4);
    // bf16 weight copies
    short* WcombB = (short*)take((size_t)PP * 512 * 512 * 2);  // [mnW | mfW] K-concat
    short* ml2Tb  = (short*)take((size_t)512 * 512 * 2);       // ml2^T (per-p, reused)
    short* WfB    = (short*)take((size_t)PP * 768 * 512 * 2);  // Wih@ml2 fused
    float* c1f    = (float*)take((size_t)PP * 768 * 4);        // Wih@ml2_b
    short* WihB  = (short*)take((size_t)PP * 768 * 512 * 2);
    short* WhhB  = (short*)take((size_t)PP * 768 * 256 * 2);
    short* W4agg = (short*)take((size_t)2048 * 256 * 2);       // [dec interleave; init interleave]
    // CSR buffers
    int* deg_e = (int*)take((size_t)NN * 4);
    int* offs_e = (int*)take((size_t)(NN + 1) * 4);
    int* cur_e = (int*)take((size_t)NN * 4);
    int* elist = (int*)take((size_t)2 * EE * 4);
    int* degB = (int*)take((size_t)BG * 4);
    int* offsB = (int*)take((size_t)(BG + 1) * 4);
    int* curB = (int*)take((size_t)BG * 4);
    int* nlist = (int*)take((size_t)NN * 4);
    if (off > ws_size) return;

    short* gi = bufD;            // [N,768] bf16 (T dead after edge_gather)
    short* gh = bufM;            // [N,768] bf16
    short* gpD = bufM;           // [N,512] bf16 (gh dead post-loop)
    short* gpI = bufD;           // [N,512] bf16 (gi dead post-loop)

    // activation pre-casts (enables global_load_lds path everywhere)
    k_castw<<<NN * SD / 1024, 256, 0, stream>>>(in_nodes, nodes_bf);
    k_castw<<<EE * SD / 1024, 256, 0, stream>>>(in_ef, ef_bf);
    // weight pre-casts
    for (int p = 0; p < PP; p++)
        k_cast_comb<<<512 * 512 / 1024, 256, 0, stream>>>(
            mnW + (size_t)p * 512 * 256, mfW + (size_t)p * 512 * 256,
            WcombB + (size_t)p * 512 * 512);
    k_castw<<<PP * 768 * 512 / 1024, 256, 0, stream>>>(Wih, WihB);
    k_castw<<<PP * 768 * 256 / 1024, 256, 0, stream>>>(Whh, WhhB);
    k_cast_pair<<<1024 * 256 / 1024, 256, 0, stream>>>(dec_tW, dec_gW, W4agg);
    k_cast_pair<<<1024 * 256 / 1024, 256, 0, stream>>>(init_tW, init_gW,
                                                       W4agg + 1024 * 256);
    // fused gi weights: Wf = Wih@ml2 (per p), c1 = Wih@ml2_b
    for (int p = 0; p < PP; p++) {
        k_cast_T<<<512 * 512 / 1024, 256, 0, stream>>>(
            ml2W + (size_t)p * 512 * 512, ml2Tb);
        gemm_bt<0><<<768 / 128 * 4, 256, 0, stream>>>(
            WihB + (size_t)p * 768 * 512, WihB + (size_t)p * 768 * 512, ml2Tb,
            nullptr, nullptr, WfB + (size_t)p * 768 * 512,
            nullptr, nullptr, nullptr, nullptr, nullptr,
            512, 512, 512, 4, 0);
        k_vecfuse<<<3, 256, 0, stream>>>(Wih + (size_t)p * 768 * 512,
                                         ml2b + (size_t)p * 512, c1f + p * 768);
    }

    // CSR builds (once per launch)
    hipMemsetAsync(deg_e, 0, (size_t)NN * 4, stream);
    hipMemsetAsync(cur_e, 0, (size_t)NN * 4, stream);
    hipMemsetAsync(degB, 0, (size_t)BG * 4, stream);
    hipMemsetAsync(curB, 0, (size_t)BG * 4, stream);
    k_count2<<<(EE + 255) / 256, 256, 0, stream>>>(e_src, e_dst, deg_e, EE);
    k_scan<<<1, 256, 0, stream>>>(deg_e, offs_e, NN);
    k_fill2<<<(EE + 255) / 256, 256, 0, stream>>>(e_src, e_dst, offs_e, cur_e, elist, EE);
    k_count1<<<(NN + 255) / 256, 256, 0, stream>>>(owner, degB, NN);
    k_scan<<<1, 256, 0, stream>>>(degB, offsB, BG);
    k_fill1<<<(NN + 255) / 256, 256, 0, stream>>>(owner, offsB, curB, nlist, NN);

    for (int p = 0; p < PP; p++) {
        // X = nodes[src] + nodes[dst]    [E,256] bf16 (nodes L2/L3-hot)
        k_xadd<<<EE / 8, 256, 0, stream>>>(nodes_bf, e_src, e_dst, bufC);
        // T = tanh([X|ef] @ [mnW|mfW]^T) [E,512] bf16 (K-concat GEMM, K=512)
        gemm_bt<1><<<EE / 128 * 4, 256, 0, stream>>>(
            bufC, ef_bf, WcombB + (size_t)p * 512 * 512, nullptr, nullptr,
            bufD, nullptr, nullptr, nullptr, nullptr, nullptr,
            512, 256, 512, 4, 0);
        // U[n] = sum of T over incident edges (CSR gather; msgs GEMM is FOLDED
        // into the gi weight: scatter-add commutes with the linear ml2 map)
        k_edge_gather<<<NN / 4, 256, 0, stream>>>(bufD, offs_e, elist, bufI);
        // gi = U @ (Wih@ml2)^T + deg*(Wih@ml2_b) + bih   [N,768] bf16
        gemm_bt<3><<<NN / 128 * 6, 256, 0, stream>>>(
            bufI, bufI, WfB + (size_t)p * 768 * 512,
            bih + (size_t)p * 768, c1f + p * 768,
            gi, nullptr, nullptr, nullptr, nullptr, deg_e,
            512, 512, 768, 6, 0);
        // gh = nodes @ Whh.T + bhh       [N,768] bf16 (into bufM)
        gemm_bt<0><<<NN / 128 * 6, 256, 0, stream>>>(
            nodes_bf, nodes_bf, WhhB + (size_t)p * 768 * 256, bhh + (size_t)p * 768,
            nullptr, gh, nullptr, nullptr, nullptr, nullptr, nullptr,
            256, 256, 768, 6, 0);
        // GRU combine -> nodes_bf (in place, bf16 state)
        k_gru<<<NN / 4, 256, 0, stream>>>(gi, gh, nodes_bf, owner, running);
    }

    // both aggregators in ONE routed GEMM (NC=2048: cols<1024 dec, >=1024 init)
    gemm_bt<4><<<NN / 128 * 16, 256, 0, stream>>>(
        nodes_bf, nodes_bf, W4agg, dec_tb, dec_gb,
        nullptr, gpD, gpI, init_tb, init_gb, nullptr,
        256, 256, 2048, 16, 1024);
    k_owner_reduce<<<BG, 256, 0, stream>>>(gpD, offsB, nlist, aggD);
    k_owner_reduce<<<BG, 256, 0, stream>>>(gpI, offsB, nlist, aggI);

    k_logits<<<BG, 128, 0, stream>>>(aggD, ntdW, ntdb, logitsF, outL);
    k_loss<<<1, 512, 0, stream>>>(logitsF, reft, running, outLoss);
    k_newfeat<<<BG, 256, 0, stream>>>(aggI, nte, reft, f1W, f1b, f2W, outNF);
}

// Round 11
// 1625.599 us; speedup vs baseline: 1.4532x; 1.0206x over previous
//
#include <hip/hip_runtime.h>
#include <hip/hip_bf16.h>
#include <math.h>

// Problem constants: B,N,E,S,A,P,T
#define BG 512
#define NN 65536
#define EE 131072
#define SD 256
#define AD 512
#define PP 2
#define TD 64

typedef __attribute__((ext_vector_type(8))) short sx8;   // 8 bf16 (4 VGPRs)
typedef __attribute__((ext_vector_type(4))) short sx4;
typedef __attribute__((ext_vector_type(4))) float fx4;

__device__ __forceinline__ float bs2f(short s) {
    union { unsigned u; float f; } x; x.u = ((unsigned)(unsigned short)s) << 16; return x.f;
}
__device__ __forceinline__ short f2bs(float f) {
    union { float f; unsigned u; } x; x.f = f;
    unsigned r = x.u + 0x7fffu + ((x.u >> 16) & 1u);   // RNE (finite inputs)
    return (short)(r >> 16);
}
// branch-free fast tanh/sigmoid (v_exp_f32 path, clamped -> no inf/NaN)
__device__ __forceinline__ float fast_tanh(float x) {
    float xc = fminf(fmaxf(x, -15.f), 15.f);
    float e = __expf(2.f * xc);
    return __fdividef(e - 1.f, e + 1.f);
}
__device__ __forceinline__ float fast_sigm(float x) {
    float xc = fminf(fmaxf(x, -30.f), 30.f);
    float e = __expf(-xc);
    return __fdividef(1.f, 1.f + e);
}
__device__ __forceinline__ bool run_flag(const void* runv, int idx) {
    const unsigned char* r8 = (const unsigned char*)runv;
    const int* r32 = (const int*)runv;
    return (r8[idx] != 0) || (r32[idx] != 0);
}

// async global->LDS, 16B per lane; dest = wave-uniform base + lane*16
__device__ __forceinline__ void gload16(const short* g, short* l) {
    __builtin_amdgcn_global_load_lds(
        (const __attribute__((address_space(1))) void*)g,
        (__attribute__((address_space(3))) void*)l, 16, 0, 0);
}

// ---------------------------------------------------------------------------
// 128x128-tile bf16-MFMA GEMM:  C[m,n] = sum_k A'[m,k] * W[n,k]  (+bias[n])
// A' is the K-CONCAT of two operands: cols [0,Ksp) from Abp (row stride Ksp),
// cols [Ksp,K) from Abp2 (row stride K-Ksp). Normal GEMMs pass Ksp=K.
// A,W bf16 k-contiguous. global_load_lds staging, DOUBLE-BUFFERED (round-5
// structure, one __syncthreads per K-step). __launch_bounds__(256,4): bound=5
// spills MFMA accumulators (unified VGPR+AGPR ~124 regs/wave needed).
// LDS XOR-swizzle on staging (pre-swizzled global src + read-side XOR).
// 1-D grid, n-tile fastest + XCD-chunk swizzle (nwg%8==0 at all call sites).
// NC is only the C row STRIDE (may exceed computed cols — used to write the
// Wf block straight into the wider Wgru matrix).
// EPI 0/1/3 use SWAPPED mfma operands -> lane&15 = row m, regs = 4 consec
// cols: 8B vector stores (per-instruction coalesced).
//   EPI=0: store bf16 C (+bias)
//   EPI=1: store bf16 tanh(C)             (fused T, no bias)
//   EPI=3: store bf16 C + deg[m]*bias2[n] + bias[n]   (fused-GRU / fused-gi)
//   EPI=4: (unswapped) paired cols, 16-row interleaved W, ROUTED on nsplit:
//          d=acc[ni]+tb[rc], g=sigm(acc[ni+1]+gb[rc]); store BF16 d*g
// ---------------------------------------------------------------------------
template<int EPI>
__launch_bounds__(256, 4)
__global__ void gemm_bt(const short* __restrict__ Abp, const short* __restrict__ Abp2,
                        const short* __restrict__ Wp,
                        const float* __restrict__ bias, const float* __restrict__ bias2,
                        short* __restrict__ Cout, short* __restrict__ Fout,
                        short* __restrict__ FoutB,
                        const float* __restrict__ biasB, const float* __restrict__ biasB2,
                        const int* __restrict__ degp,
                        int K, int Ksp, int NC, int NT, int nsplit)
{
    __shared__ __align__(16) short sA[2 * 4096];
    __shared__ __align__(16) short sB[2 * 4096];
    const int t = threadIdx.x;
    const int lane = t & 63;
    const int w = t >> 6;

    // XCD-chunk swizzle (m157): blocks sharing an A panel run on one XCD.
    const int nwg = gridDim.x;
    const int q = nwg >> 3;                     // nwg % 8 == 0 at every call site
    const int wg = (blockIdx.x & 7) * q + (blockIdx.x >> 3);
    const int mt = wg / NT;
    const int nt = wg - mt * NT;                // n fastest -> A-panel reuse in L2
    const int m0 = mt * 128;
    const int n0 = nt * 128;

    const int wm = (w >> 1) * 64;
    const int wn = (w & 1) * 64;
    const int lr = lane & 15;
    const int lg = lane >> 4;

    fx4 acc[4][4];
#pragma unroll
    for (int i = 0; i < 4; i++)
#pragma unroll
        for (int j = 0; j < 4; j++) { fx4 z = {0.f, 0.f, 0.f, 0.f}; acc[i][j] = z; }

    // staging: thread t covers row r=t>>2, 16B block cblk (XOR-swizzled source
    // so that physical LDS block (t&3) holds logical block (t&3)^((r>>1)&3)).
    // LDS dest stays linear: byte t*16 within each 64-row half (rule #21).
    const int r = t >> 2;
    const int cblk = (t & 3) ^ ((r >> 1) & 3);
    const short* gA  = Abp  + (size_t)(m0 + r) * Ksp + cblk * 8;
    const short* gA2 = Abp2 + (size_t)(m0 + r) * (K - Ksp) + cblk * 8;
    const short* gB  = Wp + (size_t)(n0 + r) * K + cblk * 8;
    const size_t rsA  = (size_t)64 * Ksp;
    const size_t rsA2 = (size_t)64 * (K - Ksp);
    const size_t rsB  = (size_t)64 * K;         // (r+64)>>1 & 3 == r>>1 & 3

    auto STAGE = [&](int b, int kk) {
        const short* a0 = (kk < Ksp) ? (gA + kk) : (gA2 + (kk - Ksp));
        const size_t rs = (kk < Ksp) ? rsA : rsA2;
        gload16(a0,            sA + b * 4096 + w * 512);
        gload16(a0 + rs,       sA + b * 4096 + 2048 + w * 512);
        gload16(gB + kk,       sB + b * 4096 + w * 512);
        gload16(gB + kk + rsB, sB + b * 4096 + 2048 + w * 512);
    };

    STAGE(0, 0);

    // EPI=3: hoist per-row degree loads (issue-early; epilogue-only use).
    float dgv[4];
    if (EPI == 3) {
#pragma unroll
        for (int mi = 0; mi < 4; mi++)
            dgv[mi] = (float)degp[m0 + wm + mi * 16 + lr];
    }

    __syncthreads();                            // tile 0 ready
    int buf = 0;
    const int xa = (lr >> 1) & 3;               // read-side XOR row term
    for (int kk = 0; kk < K; kk += 32) {
        if (kk + 32 < K) STAGE(buf ^ 1, kk + 32);   // prefetch next tile
        const short* cA = sA + buf * 4096;
        const short* cB = sB + buf * 4096;
        sx8 af[4], bfr[4];
#pragma unroll
        for (int mi = 0; mi < 4; mi++)
            af[mi] = *(const sx8*)(cA + (wm + mi * 16 + lr) * 32 + (lg ^ xa) * 8);
#pragma unroll
        for (int ni = 0; ni < 4; ni++)
            bfr[ni] = *(const sx8*)(cB + (wn + ni * 16 + lr) * 32 + (lg ^ xa) * 8);
#pragma unroll
        for (int mi = 0; mi < 4; mi++)
#pragma unroll
            for (int ni = 0; ni < 4; ni++) {
                if (EPI == 4)       // normal: col=lane&15 -> n
                    acc[mi][ni] = __builtin_amdgcn_mfma_f32_16x16x32_bf16(
                        af[mi], bfr[ni], acc[mi][ni], 0, 0, 0);
                else                // swapped: col=lane&15 -> m, regs -> 4 consec n
                    acc[mi][ni] = __builtin_amdgcn_mfma_f32_16x16x32_bf16(
                        bfr[ni], af[mi], acc[mi][ni], 0, 0, 0);
            }
        __syncthreads();                        // drains vmcnt (next tile) + lgkm
        buf ^= 1;
    }

    if (EPI == 4) {
        // routed: n0 < nsplit -> Fout/bias/bias2, else FoutB/biasB/biasB2
        const bool useB = (n0 >= nsplit);
        short* fo = useB ? FoutB : Fout;
        const float* tb = useB ? biasB : bias;
        const float* gb = useB ? biasB2 : bias2;
        const int ln0 = useB ? (n0 - nsplit) : n0;
        // D layout: col = lane&15 (n within 16), row = (lane>>4)*4 + reg (m)
#pragma unroll
        for (int mi = 0; mi < 4; mi++) {
#pragma unroll
            for (int rg = 0; rg < 4; rg++) {
                const int m = m0 + wm + mi * 16 + lg * 4 + rg;
#pragma unroll
                for (int ni = 0; ni < 4; ni += 2) {
                    const int rc = (((ln0 + wn + ni * 16) >> 5) << 4) + lr;
                    float dv = acc[mi][ni][rg] + tb[rc];
                    float gv = fast_sigm(acc[mi][ni + 1][rg] + gb[rc]);
                    fo[(size_t)m * 512 + rc] = f2bs(dv * gv);
                }
            }
        }
    } else {
        // swapped D layout: m = m0+wm+mi*16+(lane&15); n = n0+wn+ni*16+lg*4+rg
#pragma unroll
        for (int mi = 0; mi < 4; mi++) {
            const int m = m0 + wm + mi * 16 + lr;
            short* co = Cout + (size_t)m * NC + n0;
#pragma unroll
            for (int ni = 0; ni < 4; ni++) {
                const int nc = wn + ni * 16 + lg * 4;
                sx4 o;
                if (EPI == 1) {
#pragma unroll
                    for (int rg = 0; rg < 4; rg++)
                        o[rg] = f2bs(fast_tanh(acc[mi][ni][rg]));
                } else if (EPI == 3) {
                    fx4 bv = *(const fx4*)(bias + n0 + nc);
                    fx4 cv = *(const fx4*)(bias2 + n0 + nc);
#pragma unroll
                    for (int rg = 0; rg < 4; rg++)
                        o[rg] = f2bs(acc[mi][ni][rg] + dgv[mi] * cv[rg] + bv[rg]);
                } else {                        // EPI == 0
                    fx4 vb = {0.f, 0.f, 0.f, 0.f};
                    if (bias) vb = *(const fx4*)(bias + n0 + nc);
#pragma unroll
                    for (int rg = 0; rg < 4; rg++)
                        o[rg] = f2bs(acc[mi][ni][rg] + vb[rg]);
                }
                *(sx4*)(co + nc) = o;
            }
        }
    }
}

// X[e,:] = nodes[src[e],:] + nodes[dst[e],:]   (bf16; nodes is L2/L3-resident)
__global__ void k_xadd(const short* __restrict__ nodes, const int* __restrict__ esrc,
                       const int* __restrict__ edst, short* __restrict__ X)
{
    size_t idx = ((size_t)blockIdx.x * 256 + threadIdx.x) * 8;
    const int e = (int)(idx >> 8);              // 256 cols per edge
    const int j = (int)(idx & 255);
    const int s = esrc[e], d = edst[e];
    sx8 a = *(const sx8*)(nodes + (size_t)s * 256 + j);
    sx8 b = *(const sx8*)(nodes + (size_t)d * 256 + j);
    sx8 o;
#pragma unroll
    for (int u = 0; u < 8; u++) o[u] = f2bs(bs2f(a[u]) + bs2f(b[u]));
    *(sx8*)(X + idx) = o;
}

// f32 -> bf16 pre-cast (count divisible by 1024)
__global__ void k_castw(const float* __restrict__ in, short* __restrict__ out)
{
    size_t i = ((size_t)blockIdx.x * 256 + threadIdx.x) * 4;
    fx4 v = *(const fx4*)(in + i);
    sx4 o;
#pragma unroll
    for (int u = 0; u < 4; u++) o[u] = f2bs(v[u]);
    *(sx4*)(out + i) = o;
}

// transpose-cast 512x512: out[k][k2] = bf16(in[k2][k])  (for W-operand layout)
__global__ void k_cast_T(const float* __restrict__ in, short* __restrict__ out)
{
    size_t i = ((size_t)blockIdx.x * 256 + threadIdx.x) * 4;   // 512*512 elems
    const int k = (int)(i >> 9);
    const int k2 = (int)(i & 511);
    sx4 o;
#pragma unroll
    for (int u = 0; u < 4; u++) o[u] = f2bs(in[(size_t)(k2 + u) * 512 + k]);
    *(sx4*)(out + i) = o;
}

// c1[i] = sum_k2 Wih[i][k2] * ml2b[k2]   (i < 768; f32)
__global__ void k_vecfuse(const float* __restrict__ Wih, const float* __restrict__ ml2b,
                          float* __restrict__ c1)
{
    const int i = blockIdx.x * 256 + threadIdx.x;
    if (i >= 768) return;
    const float* wr = Wih + (size_t)i * 512;
    float acc = 0.f;
    for (int k = 0; k < 512; k++) acc += wr[k] * ml2b[k];
    c1[i] = acc;
}

// Fill the non-Wf blocks of Wgru[1024][768]:
//   rows 0-511,  cols 512-767: Whh rows 0-511 (r,z)
//   rows 512-767,cols 512-767: 0               (inn has no nodes part)
//   rows 768-1023, all cols  : [0(512) | Whh rows 512-767]   (hn)
// The Wf block (rows 0-767, cols 0-511) is written by a GEMM (NC=768 stride).
__global__ void k_fill_gru(const short* __restrict__ Whh, short* __restrict__ out)
{
    size_t idx = ((size_t)blockIdx.x * 256 + threadIdx.x) * 4;  // 1024*768 elems
    const int o = (int)(idx / 768);
    const int k = (int)(idx % 768);
    if (o < 768 && k < 512) return;             // Wf region (GEMM-written)
    sx4 v = {0, 0, 0, 0};
    if (k >= 512) {
        if (o < 512)       v = *(const sx4*)(Whh + (size_t)o * 256 + (k - 512));
        else if (o >= 768) v = *(const sx4*)(Whh + (size_t)(o - 256) * 256 + (k - 512));
    }
    *(sx4*)(out + idx) = v;
}

// combined GRU bias vectors: bg[1024], cg[1024]
//   o<512:  b=bih[o]+bhh[o], c=c1[o]   (r,z sums)
//   512-767: b=bih[o],       c=c1[o]   (inn)
//   768+:    b=bhh[o-256],   c=0       (hn)
__global__ void k_grubias(const float* __restrict__ bih, const float* __restrict__ bhh,
                          const float* __restrict__ c1,
                          float* __restrict__ bg, float* __restrict__ cg)
{
    const int o = blockIdx.x * 256 + threadIdx.x;
    if (o >= 1024) return;
    float b, c;
    if (o < 512)      { b = bih[o] + bhh[o]; c = c1[o]; }
    else if (o < 768) { b = bih[o];          c = c1[o]; }
    else              { b = bhh[o - 256];    c = 0.f;   }
    bg[o] = b; cg[o] = c;
}

// K-concat weight cast: out[n][k] (512x512): k<256 -> mn[n][k], else mf[n][k-256]
__global__ void k_cast_comb(const float* __restrict__ mn, const float* __restrict__ mf,
                            short* __restrict__ out)
{
    size_t i = ((size_t)blockIdx.x * 256 + threadIdx.x) * 4;   // 512*512 elems
    const int n = (int)(i >> 9);
    const int k = (int)(i & 511);
    const float* W = (k < 256) ? (mn + (size_t)n * 256 + k)
                               : (mf + (size_t)n * 256 + (k - 256));
    fx4 v = *(const fx4*)W;
    sx4 o;
#pragma unroll
    for (int u = 0; u < 4; u++) o[u] = f2bs(v[u]);
    *(sx4*)(out + i) = o;
}

// stacked data/gate weights, 16-row interleave: out row r2 (of 1024):
// pair=r2>>5, kind=(r2>>4)&1, within=r2&15 -> src row pair*16+within of tW/gW
__global__ void k_cast_pair(const float* __restrict__ tW, const float* __restrict__ gW,
                            short* __restrict__ out)
{
    size_t i = ((size_t)blockIdx.x * 256 + threadIdx.x) * 4;   // 1024*256 elems
    const int r2 = (int)(i >> 8);
    const int c = (int)(i & 255);
    const int src = ((r2 >> 5) << 4) | (r2 & 15);
    const float* W = ((r2 >> 4) & 1) ? gW : tW;
    fx4 v = *(const fx4*)(W + (size_t)src * 256 + c);
    sx4 o;
#pragma unroll
    for (int u = 0; u < 4; u++) o[u] = f2bs(v[u]);
    *(sx4*)(out + i) = o;
}

// ---------------- CSR build ----------------
__global__ void k_count2(const int* __restrict__ a, const int* __restrict__ b,
                         int* __restrict__ deg, int n)
{
    int i = blockIdx.x * 256 + threadIdx.x;
    if (i < n) { atomicAdd(&deg[a[i]], 1); atomicAdd(&deg[b[i]], 1); }
}
__global__ void k_count1(const int* __restrict__ a, int* __restrict__ deg, int n)
{
    int i = blockIdx.x * 256 + threadIdx.x;
    if (i < n) atomicAdd(&deg[a[i]], 1);
}
// exclusive scan, single block of 256 threads, n divisible by 256
__global__ void k_scan(const int* __restrict__ deg, int* __restrict__ offs, int n)
{
    __shared__ int part[256];
    const int t = threadIdx.x;
    const int chunk = n >> 8;
    const int base = t * chunk;
    int s = 0;
    for (int i = 0; i < chunk; i++) s += deg[base + i];
    part[t] = s;
    __syncthreads();
    for (int off = 1; off < 256; off <<= 1) {
        int v = (t >= off) ? part[t - off] : 0;
        __syncthreads();
        part[t] += v;
        __syncthreads();
    }
    int run = (t > 0) ? part[t - 1] : 0;
    for (int i = 0; i < chunk; i++) {
        offs[base + i] = run;
        run += deg[base + i];
    }
    if (t == 255) offs[n] = part[255];
}
__global__ void k_fill2(const int* __restrict__ a, const int* __restrict__ b,
                        const int* __restrict__ offs, int* __restrict__ cur,
                        int* __restrict__ elist, int n)
{
    int i = blockIdx.x * 256 + threadIdx.x;
    if (i < n) {
        int p = atomicAdd(&cur[a[i]], 1); elist[offs[a[i]] + p] = i;
        int q = atomicAdd(&cur[b[i]], 1); elist[offs[b[i]] + q] = i;
    }
}
__global__ void k_fill1(const int* __restrict__ own, const int* __restrict__ offs,
                        int* __restrict__ cur, int* __restrict__ nlist, int n)
{
    int i = blockIdx.x * 256 + threadIdx.x;
    if (i < n) {
        int p = atomicAdd(&cur[own[i]], 1); nlist[offs[own[i]] + p] = i;
    }
}

// U[n,:] = sum over incident entries of T[e,:]  (bf16 in, bf16 out)
__global__ void k_edge_gather(const short* __restrict__ msgs, const int* __restrict__ offs,
                              const int* __restrict__ elist, short* __restrict__ inp)
{
    const int node = blockIdx.x * 4 + (threadIdx.x >> 6);  // 4 waves, 1 node each
    const int c = (threadIdx.x & 63) * 8;
    const int s0 = offs[node], s1 = offs[node + 1];
    float acc[8] = {0.f, 0.f, 0.f, 0.f, 0.f, 0.f, 0.f, 0.f};
    for (int s = s0; s < s1; s++) {
        const int e = elist[s];
        sx8 v = *(const sx8*)(msgs + (size_t)e * 512 + c);
#pragma unroll
        for (int u = 0; u < 8; u++) acc[u] += bs2f(v[u]);
    }
    sx8 o;
#pragma unroll
    for (int u = 0; u < 8; u++) o[u] = f2bs(acc[u]);
    *(sx8*)(inp + (size_t)node * 512 + c) = o;
}

// agg[b,:] = sum over nodes of owner b of gp[n,:]   (bf16 in, f32 accum/out)
__global__ void k_owner_reduce(const short* __restrict__ gp, const int* __restrict__ offsB,
                               const int* __restrict__ nlist, float* __restrict__ agg)
{
    const int b = blockIdx.x, t = threadIdx.x;   // 256 threads, 2 cols each
    const int s0 = offsB[b], s1 = offsB[b + 1];
    float a0 = 0.f, a1 = 0.f;
    for (int s = s0; s < s1; s++) {
        const int n = nlist[s];
        const short* pp = gp + (size_t)n * 512 + t * 2;
        a0 += bs2f(pp[0]); a1 += bs2f(pp[1]);
    }
    agg[(size_t)b * 512 + t * 2] = a0;
    agg[(size_t)b * 512 + t * 2 + 1] = a1;
}

// GRU combine from fused G[N,1024]: chunks {r-sum, z-sum, inn, hn} (biases
// baked in the GEMM epilogue). State bf16, updated in place.
__global__ void k_gru(const short* __restrict__ G, short* __restrict__ nodes,
                      const int* __restrict__ owner, const void* __restrict__ runv)
{
    const int n = blockIdx.x * 4 + (threadIdx.x >> 6);   // 4 nodes/block
    const int t = threadIdx.x & 63;                      // 64 lanes, 4 cols each
    const bool run = run_flag(runv, owner[n]);
    const size_t gb = (size_t)n * 1024 + t * 4;
    sx4 grr = *(const sx4*)(G + gb);
    sx4 grz = *(const sx4*)(G + gb + 256);
    sx4 gin = *(const sx4*)(G + gb + 512);
    sx4 ghn = *(const sx4*)(G + gb + 768);
    const size_t nbase = (size_t)n * 256 + t * 4;
    sx4 old4 = *(const sx4*)(nodes + nbase);
    sx4 outb;
#pragma unroll
    for (int u = 0; u < 4; u++) {
        float old = bs2f(old4[u]);
        float rr = fast_sigm(bs2f(grr[u]));
        float zz = fast_sigm(bs2f(grz[u]));
        float nn = fast_tanh(bs2f(gin[u]) + rr * bs2f(ghn[u]));
        float nv = (1.f - zz) * nn + zz * old;
        outb[u] = run ? f2bs(nv) : old4[u];      // !run: bit-identical writeback
    }
    *(sx4*)(nodes + nbase) = outb;
}

// logits[b,:] = aggD[b,:] @ ntd_W.T + ntd_b   (f32)
__global__ void k_logits(const float* __restrict__ agg, const float* __restrict__ Wt,
                         const float* __restrict__ bt, float* __restrict__ logitsF,
                         float* __restrict__ outL)
{
    __shared__ float row[512];
    const int b = blockIdx.x, t = threadIdx.x;
    for (int k = t; k < 512; k += 128) row[k] = agg[(size_t)b * 512 + k];
    __syncthreads();
    if (t < TD + 1) {
        float acc = bt[t];
        const float* wr = Wt + (size_t)t * 512;
        for (int k = 0; k < 512; k++) acc += row[k] * wr[k];
        logitsF[b * (TD + 1) + t] = acc;
        outL[b * (TD + 1) + t] = acc;
    }
}

__global__ void k_loss(const float* __restrict__ logitsF, const int* __restrict__ reft,
                       const void* __restrict__ runv, float* __restrict__ outLoss)
{
    __shared__ float red[512];
    const int b = threadIdx.x;
    const float* lr = logitsF + b * (TD + 1);
    float mx = lr[0];
    for (int k = 1; k < TD + 1; k++) mx = fmaxf(mx, lr[k]);
    float se = 0.f;
    for (int k = 0; k < TD + 1; k++) se += expf(lr[k] - mx);
    const int sel = reft[b] + 1;
    float pe = logf(se) + mx - lr[sel];
    red[b] = run_flag(runv, b) ? pe : 0.f;
    __syncthreads();
    for (int s = 256; s > 0; s >>= 1) {
        if (b < s) red[b] += red[b + s];
        __syncthreads();
    }
    if (b == 0) outLoss[0] = red[0] / (float)BG;
}

__global__ void k_newfeat(const float* __restrict__ aggi, const float* __restrict__ nte,
                          const int* __restrict__ reft, const float* __restrict__ f1W,
                          const float* __restrict__ f1b, const float* __restrict__ f2W,
                          float* __restrict__ outNF)
{
    __shared__ float emb[256];
    __shared__ float ag[512];
    const int b = blockIdx.x, t = threadIdx.x;
    const int rt = reft[b];
    emb[t] = nte[(size_t)rt * 256 + t];
    ag[t] = aggi[(size_t)b * 512 + t];
    ag[t + 256] = aggi[(size_t)b * 512 + 256 + t];
    __syncthreads();
    float acc = f1b[t];
    const float* w1 = f1W + (size_t)t * 256;
    for (int k = 0; k < 256; k++) acc += emb[k] * w1[k];
    const float* w2 = f2W + (size_t)t * 512;
    for (int a = 0; a < 512; a++) acc += ag[a] * w2[a];
    outNF[(size_t)b * 256 + t] = acc;
}

extern "C" void kernel_launch(void* const* d_in, const int* in_sizes, int n_in,
                              void* d_out, int out_size, void* d_ws, size_t ws_size,
                              hipStream_t stream)
{
    (void)in_sizes; (void)n_in; (void)out_size;
    const float* in_nodes = (const float*)d_in[0];
    const float* in_ef    = (const float*)d_in[1];
    const int*   e_src    = (const int*)d_in[2];
    const int*   e_dst    = (const int*)d_in[3];
    const int*   owner    = (const int*)d_in[4];
    const void*  running  = d_in[5];
    const int*   reft     = (const int*)d_in[6];
    const float* dec_tW = (const float*)d_in[7];
    const float* dec_tb = (const float*)d_in[8];
    const float* dec_gW = (const float*)d_in[9];
    const float* dec_gb = (const float*)d_in[10];
    const float* init_tW = (const float*)d_in[11];
    const float* init_tb = (const float*)d_in[12];
    const float* init_gW = (const float*)d_in[13];
    const float* init_gb = (const float*)d_in[14];
    const float* ntdW = (const float*)d_in[15];
    const float* ntdb = (const float*)d_in[16];
    const float* nte  = (const float*)d_in[17];
    const float* f1W  = (const float*)d_in[18];
    const float* f1b  = (const float*)d_in[19];
    const float* f2W  = (const float*)d_in[20];
    const float* mnW  = (const float*)d_in[21];
    const float* mfW  = (const float*)d_in[22];
    const float* ml2W = (const float*)d_in[23];
    const float* ml2b = (const float*)d_in[24];
    const float* Wih  = (const float*)d_in[25];
    const float* Whh  = (const float*)d_in[26];
    const float* bih  = (const float*)d_in[27];
    const float* bhh  = (const float*)d_in[28];

    float* outL    = (float*)d_out;                        // [512,65] f32
    float* outNF   = outL + BG * (TD + 1);                 // [512,256] f32
    float* outLoss = outNF + BG * SD;                      // [1] f32

    size_t off = 0;
    auto take = [&](size_t bytes) -> void* {
        void* p = (char*)d_ws + off;
        off += (bytes + 255) & ~(size_t)255;
        return p;
    };
    short* nodes_bf  = (short*)take((size_t)NN * SD * 2);      // 33 MB bf16 state
    short* ef_bf     = (short*)take((size_t)EE * SD * 2);      // 67 MB bf16 edge feats
    short* bufC      = (short*)take((size_t)EE * SD * 2);      // X = nodes[src]+nodes[dst]
    short* bufD      = (short*)take((size_t)EE * 512 * 2);     // T, later G / gp_ini
    short* bufM      = (short*)take((size_t)EE * 512 * 2);     // gp_dec (post-loop)
    short* bufI      = (short*)take((size_t)NN * 512 * 2);     // U = sum of T
    float* aggD      = (float*)take((size_t)BG * AD * 4);
    float* aggI      = (float*)take((size_t)BG * AD * 4);
    float* logitsF   = (float*)take((size_t)BG * (TD + 1) * 4);
    // bf16 weight copies
    short* WcombB = (short*)take((size_t)PP * 512 * 512 * 2);  // [mnW | mfW] K-concat
    short* ml2Tb  = (short*)take((size_t)512 * 512 * 2);       // ml2^T (per-p, reused)
    short* WgruB  = (short*)take((size_t)PP * 1024 * 768 * 2); // fused GRU weight
    float* c1f    = (float*)take((size_t)PP * 768 * 4);        // Wih@ml2_b
    float* bgru   = (float*)take((size_t)PP * 1024 * 4);
    float* cgru   = (float*)take((size_t)PP * 1024 * 4);
    short* WihB  = (short*)take((size_t)PP * 768 * 512 * 2);
    short* WhhB  = (short*)take((size_t)PP * 768 * 256 * 2);
    short* W4agg = (short*)take((size_t)2048 * 256 * 2);       // [dec interleave; init interleave]
    // CSR buffers
    int* deg_e = (int*)take((size_t)NN * 4);
    int* offs_e = (int*)take((size_t)(NN + 1) * 4);
    int* cur_e = (int*)take((size_t)NN * 4);
    int* elist = (int*)take((size_t)2 * EE * 4);
    int* degB = (int*)take((size_t)BG * 4);
    int* offsB = (int*)take((size_t)(BG + 1) * 4);
    int* curB = (int*)take((size_t)BG * 4);
    int* nlist = (int*)take((size_t)NN * 4);
    if (off > ws_size) return;

    short* G   = bufD;           // [N,1024] bf16 fused GRU pre-activations
    short* gpD = bufM;           // [N,512] bf16 (post-loop)
    short* gpI = bufD;           // [N,512] bf16 (G dead post-loop)

    // activation pre-casts (enables global_load_lds path everywhere)
    k_castw<<<NN * SD / 1024, 256, 0, stream>>>(in_nodes, nodes_bf);
    k_castw<<<EE * SD / 1024, 256, 0, stream>>>(in_ef, ef_bf);
    // weight pre-casts
    for (int p = 0; p < PP; p++)
        k_cast_comb<<<512 * 512 / 1024, 256, 0, stream>>>(
            mnW + (size_t)p * 512 * 256, mfW + (size_t)p * 512 * 256,
            WcombB + (size_t)p * 512 * 512);
    k_castw<<<PP * 768 * 512 / 1024, 256, 0, stream>>>(Wih, WihB);
    k_castw<<<PP * 768 * 256 / 1024, 256, 0, stream>>>(Whh, WhhB);
    k_cast_pair<<<1024 * 256 / 1024, 256, 0, stream>>>(dec_tW, dec_gW, W4agg);
    k_cast_pair<<<1024 * 256 / 1024, 256, 0, stream>>>(init_tW, init_gW,
                                                       W4agg + 1024 * 256);
    // fused GRU weights: Wf = Wih@ml2 written into Wgru's left block (NC=768
    // row stride), Whh/zero blocks via fill kernel, biases via k_grubias.
    for (int p = 0; p < PP; p++) {
        k_cast_T<<<512 * 512 / 1024, 256, 0, stream>>>(
            ml2W + (size_t)p * 512 * 512, ml2Tb);
        gemm_bt<0><<<768 / 128 * 4, 256, 0, stream>>>(
            WihB + (size_t)p * 768 * 512, WihB + (size_t)p * 768 * 512, ml2Tb,
            nullptr, nullptr, WgruB + (size_t)p * 1024 * 768,
            nullptr, nullptr, nullptr, nullptr, nullptr,
            512, 512, 768, 4, 0);
        k_vecfuse<<<3, 256, 0, stream>>>(Wih + (size_t)p * 768 * 512,
                                         ml2b + (size_t)p * 512, c1f + p * 768);
        k_fill_gru<<<1024 * 768 / 4 / 256, 256, 0, stream>>>(
            WhhB + (size_t)p * 768 * 256, WgruB + (size_t)p * 1024 * 768);
        k_grubias<<<4, 256, 0, stream>>>(bih + (size_t)p * 768, bhh + (size_t)p * 768,
                                         c1f + p * 768, bgru + p * 1024, cgru + p * 1024);
    }

    // CSR builds (once per launch)
    hipMemsetAsync(deg_e, 0, (size_t)NN * 4, stream);
    hipMemsetAsync(cur_e, 0, (size_t)NN * 4, stream);
    hipMemsetAsync(degB, 0, (size_t)BG * 4, stream);
    hipMemsetAsync(curB, 0, (size_t)BG * 4, stream);
    k_count2<<<(EE + 255) / 256, 256, 0, stream>>>(e_src, e_dst, deg_e, EE);
    k_scan<<<1, 256, 0, stream>>>(deg_e, offs_e, NN);
    k_fill2<<<(EE + 255) / 256, 256, 0, stream>>>(e_src, e_dst, offs_e, cur_e, elist, EE);
    k_count1<<<(NN + 255) / 256, 256, 0, stream>>>(owner, degB, NN);
    k_scan<<<1, 256, 0, stream>>>(degB, offsB, BG);
    k_fill1<<<(NN + 255) / 256, 256, 0, stream>>>(owner, offsB, curB, nlist, NN);

    for (int p = 0; p < PP; p++) {
        // X = nodes[src] + nodes[dst]    [E,256] bf16 (nodes L2/L3-hot)
        k_xadd<<<EE / 8, 256, 0, stream>>>(nodes_bf, e_src, e_dst, bufC);
        // T = tanh([X|ef] @ [mnW|mfW]^T) [E,512] bf16 (K-concat GEMM, K=512)
        gemm_bt<1><<<EE / 128 * 4, 256, 0, stream>>>(
            bufC, ef_bf, WcombB + (size_t)p * 512 * 512, nullptr, nullptr,
            bufD, nullptr, nullptr, nullptr, nullptr, nullptr,
            512, 256, 512, 4, 0);
        // U[n] = sum of T over incident edges (CSR gather; ml2 folded into W)
        k_edge_gather<<<NN / 4, 256, 0, stream>>>(bufD, offs_e, elist, bufI);
        // G = [U|nodes] @ Wgru^T + deg*cgru + bgru    [N,1024] bf16
        //     chunks: {ir+hr, iz+hz, inn, hn}  (gi+gh fused, K-concat K=768)
        gemm_bt<3><<<NN / 128 * 8, 256, 0, stream>>>(
            bufI, nodes_bf, WgruB + (size_t)p * 1024 * 768,
            bgru + p * 1024, cgru + p * 1024,
            G, nullptr, nullptr, nullptr, nullptr, deg_e,
            768, 512, 1024, 8, 0);
        // GRU combine -> nodes_bf (in place, bf16 state)
        k_gru<<<NN / 4, 256, 0, stream>>>(G, nodes_bf, owner, running);
    }

    // both aggregators in ONE routed GEMM (NC=2048: cols<1024 dec, >=1024 init)
    gemm_bt<4><<<NN / 128 * 16, 256, 0, stream>>>(
        nodes_bf, nodes_bf, W4agg, dec_tb, dec_gb,
        nullptr, gpD, gpI, init_tb, init_gb, nullptr,
        256, 256, 2048, 16, 1024);
    k_owner_reduce<<<BG, 256, 0, stream>>>(gpD, offsB, nlist, aggD);
    k_owner_reduce<<<BG, 256, 0, stream>>>(gpI, offsB, nlist, aggI);

    k_logits<<<BG, 128, 0, stream>>>(aggD, ntdW, ntdb, logitsF, outL);
    k_loss<<<1, 512, 0, stream>>>(logitsF, reft, running, outLoss);
    k_newfeat<<<BG, 256, 0, stream>>>(aggI, nte, reft, f1W, f1b, f2W, outNF);
}

// Round 13
// 1606.849 us; speedup vs baseline: 1.4701x; 1.0117x over previous
//
#include <hip/hip_runtime.h>
#include <hip/hip_bf16.h>
#include <math.h>

// Problem constants: B,N,E,S,A,P,T
#define BG 512
#define NN 65536
#define EE 131072
#define SD 256
#define AD 512
#define PP 2
#define TD 64

typedef __attribute__((ext_vector_type(8))) short sx8;   // 8 bf16 (4 VGPRs)
typedef __attribute__((ext_vector_type(4))) short sx4;
typedef __attribute__((ext_vector_type(4))) float fx4;

__device__ __forceinline__ float bs2f(short s) {
    union { unsigned u; float f; } x; x.u = ((unsigned)(unsigned short)s) << 16; return x.f;
}
__device__ __forceinline__ short f2bs(float f) {
    union { float f; unsigned u; } x; x.f = f;
    unsigned r = x.u + 0x7fffu + ((x.u >> 16) & 1u);   // RNE (finite inputs)
    return (short)(r >> 16);
}
// branch-free fast tanh/sigmoid (v_exp_f32 path, clamped -> no inf/NaN)
__device__ __forceinline__ float fast_tanh(float x) {
    float xc = fminf(fmaxf(x, -15.f), 15.f);
    float e = __expf(2.f * xc);
    return __fdividef(e - 1.f, e + 1.f);
}
__device__ __forceinline__ float fast_sigm(float x) {
    float xc = fminf(fmaxf(x, -30.f), 30.f);
    float e = __expf(-xc);
    return __fdividef(1.f, 1.f + e);
}
__device__ __forceinline__ bool run_flag(const void* runv, int idx) {
    const unsigned char* r8 = (const unsigned char*)runv;
    const int* r32 = (const int*)runv;
    return (r8[idx] != 0) || (r32[idx] != 0);
}

// async global->LDS, 16B per lane; dest = wave-uniform base + lane*16
__device__ __forceinline__ void gload16(const short* g, short* l) {
    __builtin_amdgcn_global_load_lds(
        (const __attribute__((address_space(1))) void*)g,
        (__attribute__((address_space(3))) void*)l, 16, 0, 0);
}

// ---------------------------------------------------------------------------
// 128x128-tile bf16-MFMA GEMM:  C[m,n] = sum_k A'[m,k] * W[n,k]  (+bias[n])
// A' is the K-CONCAT of two operands: cols [0,Ksp) from Abp (row stride Ksp),
// cols [Ksp,K) from Abp2 (row stride K-Ksp). Normal GEMMs pass Ksp=K.
// A,W bf16 k-contiguous. global_load_lds staging, DOUBLE-BUFFERED (round-5
// structure, one __syncthreads per K-step). __launch_bounds__(256,4): bound=5
// spills MFMA accumulators (unified VGPR+AGPR ~124 regs/wave needed).
// LDS XOR-swizzle on staging (pre-swizzled global src + read-side XOR).
// 1-D grid, n-tile fastest + XCD-chunk swizzle (nwg%8==0 at all call sites).
// EPI 0/1/5 use SWAPPED mfma operands -> lane&15 = row m, regs = 4 consec
// cols (vector stores, per-instruction coalesced).
//   EPI=0: store bf16 C (+bias)  (NC = row stride)
//   EPI=1: store bf16 tanh(C)    (fused T, no bias)
//   EPI=5: FULL GRU epilogue. Wgru rows mod-4 INTERLEAVED (row = 4s+chunk,
//          chunk {0:r,1:z,2:inn,3:hn}) so acc reg rg == chunk of state col
//          s=(n>>2). v = acc + deg[m]*cg[n] + bg[n]; r=sig(v0) z=sig(v1)
//          nn=tanh(v2+r*v3); new=(1-z)nn+z*old[m][s]; store bf16 (or old
//          bits if !running[owner[m]]) to Cout[m][s]. Ping-pong state buf.
//   EPI=4: (unswapped) paired cols, 16-row interleaved W, ROUTED on nsplit:
//          d=acc[ni]+tb[rc], g=sigm(acc[ni+1]+gb[rc]); store BF16 d*g
// ---------------------------------------------------------------------------
template<int EPI>
__launch_bounds__(256, 4)
__global__ void gemm_bt(const short* __restrict__ Abp, const short* __restrict__ Abp2,
                        const short* __restrict__ Wp,
                        const float* __restrict__ bias, const float* __restrict__ bias2,
                        short* __restrict__ Cout, short* __restrict__ Fout,
                        short* __restrict__ FoutB,
                        const float* __restrict__ biasB, const float* __restrict__ biasB2,
                        const int* __restrict__ degp,
                        const short* __restrict__ oldp, const int* __restrict__ ownp,
                        const void* __restrict__ runv,
                        int K, int Ksp, int NC, int NT, int nsplit)
{
    __shared__ __align__(16) short sA[2 * 4096];
    __shared__ __align__(16) short sB[2 * 4096];
    const int t = threadIdx.x;
    const int lane = t & 63;
    const int w = t >> 6;

    // XCD-chunk swizzle (m157): blocks sharing an A panel run on one XCD.
    const int nwg = gridDim.x;
    const int q = nwg >> 3;                     // nwg % 8 == 0 at every call site
    const int wg = (blockIdx.x & 7) * q + (blockIdx.x >> 3);
    const int mt = wg / NT;
    const int nt = wg - mt * NT;                // n fastest -> A-panel reuse in L2
    const int m0 = mt * 128;
    const int n0 = nt * 128;

    const int wm = (w >> 1) * 64;
    const int wn = (w & 1) * 64;
    const int lr = lane & 15;
    const int lg = lane >> 4;

    fx4 acc[4][4];
#pragma unroll
    for (int i = 0; i < 4; i++)
#pragma unroll
        for (int j = 0; j < 4; j++) { fx4 z = {0.f, 0.f, 0.f, 0.f}; acc[i][j] = z; }

    // staging: thread t covers row r=t>>2, 16B block cblk (XOR-swizzled source
    // so that physical LDS block (t&3) holds logical block (t&3)^((r>>1)&3)).
    // LDS dest stays linear: byte t*16 within each 64-row half (rule #21).
    const int r = t >> 2;
    const int cblk = (t & 3) ^ ((r >> 1) & 3);
    const short* gA  = Abp  + (size_t)(m0 + r) * Ksp + cblk * 8;
    const short* gA2 = Abp2 + (size_t)(m0 + r) * (K - Ksp) + cblk * 8;
    const short* gB  = Wp + (size_t)(n0 + r) * K + cblk * 8;
    const size_t rsA  = (size_t)64 * Ksp;
    const size_t rsA2 = (size_t)64 * (K - Ksp);
    const size_t rsB  = (size_t)64 * K;         // (r+64)>>1 & 3 == r>>1 & 3

    auto STAGE = [&](int b, int kk) {
        const short* a0 = (kk < Ksp) ? (gA + kk) : (gA2 + (kk - Ksp));
        const size_t rs = (kk < Ksp) ? rsA : rsA2;
        gload16(a0,            sA + b * 4096 + w * 512);
        gload16(a0 + rs,       sA + b * 4096 + 2048 + w * 512);
        gload16(gB + kk,       sB + b * 4096 + w * 512);
        gload16(gB + kk + rsB, sB + b * 4096 + 2048 + w * 512);
    };

    STAGE(0, 0);

    // EPI=5: hoist per-row degree / run-flag loads (issue-early).
    float dgv[4];
    bool rn[4];
    if (EPI == 5) {
#pragma unroll
        for (int mi = 0; mi < 4; mi++) {
            const int m = m0 + wm + mi * 16 + lr;
            dgv[mi] = (float)degp[m];
            rn[mi] = run_flag(runv, ownp[m]);
        }
    }

    __syncthreads();                            // tile 0 ready
    int buf = 0;
    const int xa = (lr >> 1) & 3;               // read-side XOR row term
    for (int kk = 0; kk < K; kk += 32) {
        if (kk + 32 < K) STAGE(buf ^ 1, kk + 32);   // prefetch next tile
        const short* cA = sA + buf * 4096;
        const short* cB = sB + buf * 4096;
        sx8 af[4], bfr[4];
#pragma unroll
        for (int mi = 0; mi < 4; mi++)
            af[mi] = *(const sx8*)(cA + (wm + mi * 16 + lr) * 32 + (lg ^ xa) * 8);
#pragma unroll
        for (int ni = 0; ni < 4; ni++)
            bfr[ni] = *(const sx8*)(cB + (wn + ni * 16 + lr) * 32 + (lg ^ xa) * 8);
#pragma unroll
        for (int mi = 0; mi < 4; mi++)
#pragma unroll
            for (int ni = 0; ni < 4; ni++) {
                if (EPI == 4)       // normal: col=lane&15 -> n
                    acc[mi][ni] = __builtin_amdgcn_mfma_f32_16x16x32_bf16(
                        af[mi], bfr[ni], acc[mi][ni], 0, 0, 0);
                else                // swapped: col=lane&15 -> m, regs -> 4 consec n
                    acc[mi][ni] = __builtin_amdgcn_mfma_f32_16x16x32_bf16(
                        bfr[ni], af[mi], acc[mi][ni], 0, 0, 0);
            }
        __syncthreads();                        // drains vmcnt (next tile) + lgkm
        buf ^= 1;
    }

    if (EPI == 4) {
        // routed: n0 < nsplit -> Fout/bias/bias2, else FoutB/biasB/biasB2
        const bool useB = (n0 >= nsplit);
        short* fo = useB ? FoutB : Fout;
        const float* tb = useB ? biasB : bias;
        const float* gb = useB ? biasB2 : bias2;
        const int ln0 = useB ? (n0 - nsplit) : n0;
        // D layout: col = lane&15 (n within 16), row = (lane>>4)*4 + reg (m)
#pragma unroll
        for (int mi = 0; mi < 4; mi++) {
#pragma unroll
            for (int rg = 0; rg < 4; rg++) {
                const int m = m0 + wm + mi * 16 + lg * 4 + rg;
#pragma unroll
                for (int ni = 0; ni < 4; ni += 2) {
                    const int rc = (((ln0 + wn + ni * 16) >> 5) << 4) + lr;
                    float dv = acc[mi][ni][rg] + tb[rc];
                    float gv = fast_sigm(acc[mi][ni + 1][rg] + gb[rc]);
                    fo[(size_t)m * 512 + rc] = f2bs(dv * gv);
                }
            }
        }
    } else if (EPI == 5) {
        // swapped layout; reg rg == gate chunk, state col s = (n0+wn+ni*16+lg*4)>>2
#pragma unroll
        for (int mi = 0; mi < 4; mi++) {
            const int m = m0 + wm + mi * 16 + lr;
#pragma unroll
            for (int ni = 0; ni < 4; ni++) {
                const int cbase = n0 + wn + ni * 16 + lg * 4;   // ≡ 0 mod 4
                const int s = cbase >> 2;
                fx4 bv = *(const fx4*)(bias + cbase);
                fx4 cv = *(const fx4*)(bias2 + cbase);
                float v0 = acc[mi][ni][0] + dgv[mi] * cv[0] + bv[0];
                float v1 = acc[mi][ni][1] + dgv[mi] * cv[1] + bv[1];
                float v2 = acc[mi][ni][2] + dgv[mi] * cv[2] + bv[2];
                float v3 = acc[mi][ni][3] + dgv[mi] * cv[3] + bv[3];
                float rr = fast_sigm(v0);
                float zz = fast_sigm(v1);
                float nn = fast_tanh(v2 + rr * v3);
                const size_t oidx = (size_t)m * 256 + s;
                short oldb = oldp[oidx];
                float nv = (1.f - zz) * nn + zz * bs2f(oldb);
                Cout[oidx] = rn[mi] ? f2bs(nv) : oldb;
            }
        }
    } else {
        // swapped D layout: m = m0+wm+mi*16+(lane&15); n = n0+wn+ni*16+lg*4+rg
#pragma unroll
        for (int mi = 0; mi < 4; mi++) {
            const int m = m0 + wm + mi * 16 + lr;
            short* co = Cout + (size_t)m * NC + n0;
#pragma unroll
            for (int ni = 0; ni < 4; ni++) {
                const int nc = wn + ni * 16 + lg * 4;
                sx4 o;
                if (EPI == 1) {
#pragma unroll
                    for (int rg = 0; rg < 4; rg++)
                        o[rg] = f2bs(fast_tanh(acc[mi][ni][rg]));
                } else {                        // EPI == 0
                    fx4 vb = {0.f, 0.f, 0.f, 0.f};
                    if (bias) vb = *(const fx4*)(bias + n0 + nc);
#pragma unroll
                    for (int rg = 0; rg < 4; rg++)
                        o[rg] = f2bs(acc[mi][ni][rg] + vb[rg]);
                }
                *(sx4*)(co + nc) = o;
            }
        }
    }
}

// X[e,:] = nodes[src[e],:] + nodes[dst[e],:]   (bf16; nodes is L2/L3-resident)
__global__ void k_xadd(const short* __restrict__ nodes, const int* __restrict__ esrc,
                       const int* __restrict__ edst, short* __restrict__ X)
{
    size_t idx = ((size_t)blockIdx.x * 256 + threadIdx.x) * 8;
    const int e = (int)(idx >> 8);              // 256 cols per edge
    const int j = (int)(idx & 255);
    const int s = esrc[e], d = edst[e];
    sx8 a = *(const sx8*)(nodes + (size_t)s * 256 + j);
    sx8 b = *(const sx8*)(nodes + (size_t)d * 256 + j);
    sx8 o;
#pragma unroll
    for (int u = 0; u < 8; u++) o[u] = f2bs(bs2f(a[u]) + bs2f(b[u]));
    *(sx8*)(X + idx) = o;
}

// f32 -> bf16 pre-cast (count divisible by 1024)
__global__ void k_castw(const float* __restrict__ in, short* __restrict__ out)
{
    size_t i = ((size_t)blockIdx.x * 256 + threadIdx.x) * 4;
    fx4 v = *(const fx4*)(in + i);
    sx4 o;
#pragma unroll
    for (int u = 0; u < 4; u++) o[u] = f2bs(v[u]);
    *(sx4*)(out + i) = o;
}

// transpose-cast 512x512: out[k][k2] = bf16(in[k2][k])  (for W-operand layout)
__global__ void k_cast_T(const float* __restrict__ in, short* __restrict__ out)
{
    size_t i = ((size_t)blockIdx.x * 256 + threadIdx.x) * 4;   // 512*512 elems
    const int k = (int)(i >> 9);
    const int k2 = (int)(i & 511);
    sx4 o;
#pragma unroll
    for (int u = 0; u < 4; u++) o[u] = f2bs(in[(size_t)(k2 + u) * 512 + k]);
    *(sx4*)(out + i) = o;
}

// c1[i] = sum_k2 Wih[i][k2] * ml2b[k2]   (i < 768; f32)
__global__ void k_vecfuse(const float* __restrict__ Wih, const float* __restrict__ ml2b,
                          float* __restrict__ c1)
{
    const int i = blockIdx.x * 256 + threadIdx.x;
    if (i >= 768) return;
    const float* wr = Wih + (size_t)i * 512;
    float acc = 0.f;
    for (int k = 0; k < 512; k++) acc += wr[k] * ml2b[k];
    c1[i] = acc;
}

// Build mod-4 interleaved Wgru4[1024][768] from WfB[768][512] and Whh[768][256]:
// row r' = 4s+c, c in {0:r,1:z,2:inn,3:hn}:
//   k<512 : c<3 ? WfB[c*256+s][k]      : 0
//   k>=512: c==2 ? 0 : Whh[(c==3?512:c*256)+s][k-512]
__global__ void k_fill_gru4(const short* __restrict__ WfB, const short* __restrict__ Whh,
                            short* __restrict__ out)
{
    size_t idx = ((size_t)blockIdx.x * 256 + threadIdx.x) * 4;  // 1024*768 elems
    const int rp = (int)(idx / 768);
    const int k = (int)(idx % 768);
    const int s = rp >> 2, c = rp & 3;
    sx4 v = {0, 0, 0, 0};
    if (k < 512) {
        if (c < 3) v = *(const sx4*)(WfB + (size_t)(c * 256 + s) * 512 + k);
    } else {
        if (c != 2) {
            const int o = (c == 3 ? 512 : c * 256) + s;
            v = *(const sx4*)(Whh + (size_t)o * 256 + (k - 512));
        }
    }
    *(sx4*)(out + idx) = v;
}

// interleaved GRU bias vectors bg/cg[1024], row 4s+c:
//   c=0: b=bih[s]+bhh[s],        cg=c1[s]
//   c=1: b=bih[256+s]+bhh[256+s],cg=c1[256+s]
//   c=2: b=bih[512+s],           cg=c1[512+s]
//   c=3: b=bhh[512+s],           cg=0
__global__ void k_grubias4(const float* __restrict__ bih, const float* __restrict__ bhh,
                           const float* __restrict__ c1,
                           float* __restrict__ bg, float* __restrict__ cg)
{
    const int rp = blockIdx.x * 256 + threadIdx.x;
    if (rp >= 1024) return;
    const int s = rp >> 2, c = rp & 3;
    float b, cc;
    if (c == 0)      { b = bih[s] + bhh[s];             cc = c1[s]; }
    else if (c == 1) { b = bih[256 + s] + bhh[256 + s]; cc = c1[256 + s]; }
    else if (c == 2) { b = bih[512 + s];                cc = c1[512 + s]; }
    else             { b = bhh[512 + s];                cc = 0.f; }
    bg[rp] = b; cg[rp] = cc;
}

// K-concat weight cast: out[n][k] (512x512): k<256 -> mn[n][k], else mf[n][k-256]
__global__ void k_cast_comb(const float* __restrict__ mn, const float* __restrict__ mf,
                            short* __restrict__ out)
{
    size_t i = ((size_t)blockIdx.x * 256 + threadIdx.x) * 4;   // 512*512 elems
    const int n = (int)(i >> 9);
    const int k = (int)(i & 511);
    const float* W = (k < 256) ? (mn + (size_t)n * 256 + k)
                               : (mf + (size_t)n * 256 + (k - 256));
    fx4 v = *(const fx4*)W;
    sx4 o;
#pragma unroll
    for (int u = 0; u < 4; u++) o[u] = f2bs(v[u]);
    *(sx4*)(out + i) = o;
}

// stacked data/gate weights, 16-row interleave: out row r2 (of 1024):
// pair=r2>>5, kind=(r2>>4)&1, within=r2&15 -> src row pair*16+within of tW/gW
__global__ void k_cast_pair(const float* __restrict__ tW, const float* __restrict__ gW,
                            short* __restrict__ out)
{
    size_t i = ((size_t)blockIdx.x * 256 + threadIdx.x) * 4;   // 1024*256 elems
    const int r2 = (int)(i >> 8);
    const int c = (int)(i & 255);
    const int src = ((r2 >> 5) << 4) | (r2 & 15);
    const float* W = ((r2 >> 4) & 1) ? gW : tW;
    fx4 v = *(const fx4*)(W + (size_t)src * 256 + c);
    sx4 o;
#pragma unroll
    for (int u = 0; u < 4; u++) o[u] = f2bs(v[u]);
    *(sx4*)(out + i) = o;
}

// ---------------- CSR build ----------------
__global__ void k_count2(const int* __restrict__ a, const int* __restrict__ b,
                         int* __restrict__ deg, int n)
{
    int i = blockIdx.x * 256 + threadIdx.x;
    if (i < n) { atomicAdd(&deg[a[i]], 1); atomicAdd(&deg[b[i]], 1); }
}
__global__ void k_count1(const int* __restrict__ a, int* __restrict__ deg, int n)
{
    int i = blockIdx.x * 256 + threadIdx.x;
    if (i < n) atomicAdd(&deg[a[i]], 1);
}
// exclusive scan, single block of 256 threads, n divisible by 256
__global__ void k_scan(const int* __restrict__ deg, int* __restrict__ offs, int n)
{
    __shared__ int part[256];
    const int t = threadIdx.x;
    const int chunk = n >> 8;
    const int base = t * chunk;
    int s = 0;
    for (int i = 0; i < chunk; i++) s += deg[base + i];
    part[t] = s;
    __syncthreads();
    for (int off = 1; off < 256; off <<= 1) {
        int v = (t >= off) ? part[t - off] : 0;
        __syncthreads();
        part[t] += v;
        __syncthreads();
    }
    int run = (t > 0) ? part[t - 1] : 0;
    for (int i = 0; i < chunk; i++) {
        offs[base + i] = run;
        run += deg[base + i];
    }
    if (t == 255) offs[n] = part[255];
}
__global__ void k_fill2(const int* __restrict__ a, const int* __restrict__ b,
                        const int* __restrict__ offs, int* __restrict__ cur,
                        int* __restrict__ elist, int n)
{
    int i = blockIdx.x * 256 + threadIdx.x;
    if (i < n) {
        int p = atomicAdd(&cur[a[i]], 1); elist[offs[a[i]] + p] = i;
        int q = atomicAdd(&cur[b[i]], 1); elist[offs[b[i]] + q] = i;
    }
}
__global__ void k_fill1(const int* __restrict__ own, const int* __restrict__ offs,
                        int* __restrict__ cur, int* __restrict__ nlist, int n)
{
    int i = blockIdx.x * 256 + threadIdx.x;
    if (i < n) {
        int p = atomicAdd(&cur[own[i]], 1); nlist[offs[own[i]] + p] = i;
    }
}

// U[n,:] = sum over incident entries of T[e,:]  (bf16 in, bf16 out)
__global__ void k_edge_gather(const short* __restrict__ msgs, const int* __restrict__ offs,
                              const int* __restrict__ elist, short* __restrict__ inp)
{
    const int node = blockIdx.x * 4 + (threadIdx.x >> 6);  // 4 waves, 1 node each
    const int c = (threadIdx.x & 63) * 8;
    const int s0 = offs[node], s1 = offs[node + 1];
    float acc[8] = {0.f, 0.f, 0.f, 0.f, 0.f, 0.f, 0.f, 0.f};
    for (int s = s0; s < s1; s++) {
        const int e = elist[s];
        sx8 v = *(const sx8*)(msgs + (size_t)e * 512 + c);
#pragma unroll
        for (int u = 0; u < 8; u++) acc[u] += bs2f(v[u]);
    }
    sx8 o;
#pragma unroll
    for (int u = 0; u < 8; u++) o[u] = f2bs(acc[u]);
    *(sx8*)(inp + (size_t)node * 512 + c) = o;
}

// agg[b,:] = sum over nodes of owner b of gp[n,:]   (bf16 in, f32 accum/out)
__global__ void k_owner_reduce(const short* __restrict__ gp, const int* __restrict__ offsB,
                               const int* __restrict__ nlist, float* __restrict__ agg)
{
    const int b = blockIdx.x, t = threadIdx.x;   // 256 threads, 2 cols each
    const int s0 = offsB[b], s1 = offsB[b + 1];
    float a0 = 0.f, a1 = 0.f;
    for (int s = s0; s < s1; s++) {
        const int n = nlist[s];
        const short* pp = gp + (size_t)n * 512 + t * 2;
        a0 += bs2f(pp[0]); a1 += bs2f(pp[1]);
    }
    agg[(size_t)b * 512 + t * 2] = a0;
    agg[(size_t)b * 512 + t * 2 + 1] = a1;
}

// logits[b,:] = aggD[b,:] @ ntd_W.T + ntd_b   (f32)
__global__ void k_logits(const float* __restrict__ agg, const float* __restrict__ Wt,
                         const float* __restrict__ bt, float* __restrict__ logitsF,
                         float* __restrict__ outL)
{
    __shared__ float row[512];
    const int b = blockIdx.x, t = threadIdx.x;
    for (int k = t; k < 512; k += 128) row[k] = agg[(size_t)b * 512 + k];
    __syncthreads();
    if (t < TD + 1) {
        float acc = bt[t];
        const float* wr = Wt + (size_t)t * 512;
        for (int k = 0; k < 512; k++) acc += row[k] * wr[k];
        logitsF[b * (TD + 1) + t] = acc;
        outL[b * (TD + 1) + t] = acc;
    }
}

__global__ void k_loss(const float* __restrict__ logitsF, const int* __restrict__ reft,
                       const void* __restrict__ runv, float* __restrict__ outLoss)
{
    __shared__ float red[512];
    const int b = threadIdx.x;
    const float* lr = logitsF + b * (TD + 1);
    float mx = lr[0];
    for (int k = 1; k < TD + 1; k++) mx = fmaxf(mx, lr[k]);
    float se = 0.f;
    for (int k = 0; k < TD + 1; k++) se += expf(lr[k] - mx);
    const int sel = reft[b] + 1;
    float pe = logf(se) + mx - lr[sel];
    red[b] = run_flag(runv, b) ? pe : 0.f;
    __syncthreads();
    for (int s = 256; s > 0; s >>= 1) {
        if (b < s) red[b] += red[b + s];
        __syncthreads();
    }
    if (b == 0) outLoss[0] = red[0] / (float)BG;
}

__global__ void k_newfeat(const float* __restrict__ aggi, const float* __restrict__ nte,
                          const int* __restrict__ reft, const float* __restrict__ f1W,
                          const float* __restrict__ f1b, const float* __restrict__ f2W,
                          float* __restrict__ outNF)
{
    __shared__ float emb[256];
    __shared__ float ag[512];
    const int b = blockIdx.x, t = threadIdx.x;
    const int rt = reft[b];
    emb[t] = nte[(size_t)rt * 256 + t];
    ag[t] = aggi[(size_t)b * 512 + t];
    ag[t + 256] = aggi[(size_t)b * 512 + 256 + t];
    __syncthreads();
    float acc = f1b[t];
    const float* w1 = f1W + (size_t)t * 256;
    for (int k = 0; k < 256; k++) acc += emb[k] * w1[k];
    const float* w2 = f2W + (size_t)t * 512;
    for (int a = 0; a < 512; a++) acc += ag[a] * w2[a];
    outNF[(size_t)b * 256 + t] = acc;
}

extern "C" void kernel_launch(void* const* d_in, const int* in_sizes, int n_in,
                              void* d_out, int out_size, void* d_ws, size_t ws_size,
                              hipStream_t stream)
{
    (void)in_sizes; (void)n_in; (void)out_size;
    const float* in_nodes = (const float*)d_in[0];
    const float* in_ef    = (const float*)d_in[1];
    const int*   e_src    = (const int*)d_in[2];
    const int*   e_dst    = (const int*)d_in[3];
    const int*   owner    = (const int*)d_in[4];
    const void*  running  = d_in[5];
    const int*   reft     = (const int*)d_in[6];
    const float* dec_tW = (const float*)d_in[7];
    const float* dec_tb = (const float*)d_in[8];
    const float* dec_gW = (const float*)d_in[9];
    const float* dec_gb = (const float*)d_in[10];
    const float* init_tW = (const float*)d_in[11];
    const float* init_tb = (const float*)d_in[12];
    const float* init_gW = (const float*)d_in[13];
    const float* init_gb = (const float*)d_in[14];
    const float* ntdW = (const float*)d_in[15];
    const float* ntdb = (const float*)d_in[16];
    const float* nte  = (const float*)d_in[17];
    const float* f1W  = (const float*)d_in[18];
    const float* f1b  = (const float*)d_in[19];
    const float* f2W  = (const float*)d_in[20];
    const float* mnW  = (const float*)d_in[21];
    const float* mfW  = (const float*)d_in[22];
    const float* ml2W = (const float*)d_in[23];
    const float* ml2b = (const float*)d_in[24];
    const float* Wih  = (const float*)d_in[25];
    const float* Whh  = (const float*)d_in[26];
    const float* bih  = (const float*)d_in[27];
    const float* bhh  = (const float*)d_in[28];

    float* outL    = (float*)d_out;                        // [512,65] f32
    float* outNF   = outL + BG * (TD + 1);                 // [512,256] f32
    float* outLoss = outNF + BG * SD;                      // [1] f32

    size_t off = 0;
    auto take = [&](size_t bytes) -> void* {
        void* p = (char*)d_ws + off;
        off += (bytes + 255) & ~(size_t)255;
        return p;
    };
    short* nodesA    = (short*)take((size_t)NN * SD * 2);      // bf16 state (ping)
    short* nodesB    = (short*)take((size_t)NN * SD * 2);      // bf16 state (pong)
    short* ef_bf     = (short*)take((size_t)EE * SD * 2);      // 67 MB bf16 edge feats
    short* bufC      = (short*)take((size_t)EE * SD * 2);      // X = nodes[src]+nodes[dst]
    short* bufD      = (short*)take((size_t)EE * 512 * 2);     // T, later gp_ini
    short* bufI      = (short*)take((size_t)NN * 512 * 2);     // U, later gp_dec
    float* aggD      = (float*)take((size_t)BG * AD * 4);
    float* aggI      = (float*)take((size_t)BG * AD * 4);
    float* logitsF   = (float*)take((size_t)BG * (TD + 1) * 4);
    // bf16 weight copies
    short* WcombB = (short*)take((size_t)PP * 512 * 512 * 2);  // [mnW | mfW] K-concat
    short* ml2Tb  = (short*)take((size_t)512 * 512 * 2);       // ml2^T (per-p, reused)
    short* WfB    = (short*)take((size_t)768 * 512 * 2);       // Wih@ml2 temp (per-p)
    short* Wgru4  = (short*)take((size_t)PP * 1024 * 768 * 2); // interleaved GRU weight
    float* c1f    = (float*)take((size_t)PP * 768 * 4);        // Wih@ml2_b
    float* bgru   = (float*)take((size_t)PP * 1024 * 4);
    float* cgru   = (float*)take((size_t)PP * 1024 * 4);
    short* WihB  = (short*)take((size_t)PP * 768 * 512 * 2);
    short* WhhB  = (short*)take((size_t)PP * 768 * 256 * 2);
    short* W4agg = (short*)take((size_t)2048 * 256 * 2);       // [dec interleave; init interleave]
    // CSR buffers
    int* deg_e = (int*)take((size_t)NN * 4);
    int* offs_e = (int*)take((size_t)(NN + 1) * 4);
    int* cur_e = (int*)take((size_t)NN * 4);
    int* elist = (int*)take((size_t)2 * EE * 4);
    int* degB = (int*)take((size_t)BG * 4);
    int* offsB = (int*)take((size_t)(BG + 1) * 4);
    int* curB = (int*)take((size_t)BG * 4);
    int* nlist = (int*)take((size_t)NN * 4);
    if (off > ws_size) return;

    short* gpD = bufI;           // [N,512] bf16 (U dead post-loop)
    short* gpI = bufD;           // [N,512] bf16 (T dead post-loop)

    // activation pre-casts (enables global_load_lds path everywhere)
    k_castw<<<NN * SD / 1024, 256, 0, stream>>>(in_nodes, nodesA);
    k_castw<<<EE * SD / 1024, 256, 0, stream>>>(in_ef, ef_bf);
    // weight pre-casts
    for (int p = 0; p < PP; p++)
        k_cast_comb<<<512 * 512 / 1024, 256, 0, stream>>>(
            mnW + (size_t)p * 512 * 256, mfW + (size_t)p * 512 * 256,
            WcombB + (size_t)p * 512 * 512);
    k_castw<<<PP * 768 * 512 / 1024, 256, 0, stream>>>(Wih, WihB);
    k_castw<<<PP * 768 * 256 / 1024, 256, 0, stream>>>(Whh, WhhB);
    k_cast_pair<<<1024 * 256 / 1024, 256, 0, stream>>>(dec_tW, dec_gW, W4agg);
    k_cast_pair<<<1024 * 256 / 1024, 256, 0, stream>>>(init_tW, init_gW,
                                                       W4agg + 1024 * 256);
    // fused GRU weights: Wf = Wih@ml2 -> WfB, then mod-4 interleave into Wgru4.
    for (int p = 0; p < PP; p++) {
        k_cast_T<<<512 * 512 / 1024, 256, 0, stream>>>(
            ml2W + (size_t)p * 512 * 512, ml2Tb);
        gemm_bt<0><<<768 / 128 * 4, 256, 0, stream>>>(
            WihB + (size_t)p * 768 * 512, WihB + (size_t)p * 768 * 512, ml2Tb,
            nullptr, nullptr, WfB, nullptr, nullptr, nullptr, nullptr,
            nullptr, nullptr, nullptr, nullptr,
            512, 512, 512, 4, 0);
        k_vecfuse<<<3, 256, 0, stream>>>(Wih + (size_t)p * 768 * 512,
                                         ml2b + (size_t)p * 512, c1f + p * 768);
        k_fill_gru4<<<1024 * 768 / 4 / 256, 256, 0, stream>>>(
            WfB, WhhB + (size_t)p * 768 * 256, Wgru4 + (size_t)p * 1024 * 768);
        k_grubias4<<<4, 256, 0, stream>>>(bih + (size_t)p * 768, bhh + (size_t)p * 768,
                                          c1f + p * 768, bgru + p * 1024, cgru + p * 1024);
    }

    // CSR builds (once per launch)
    hipMemsetAsync(deg_e, 0, (size_t)NN * 4, stream);
    hipMemsetAsync(cur_e, 0, (size_t)NN * 4, stream);
    hipMemsetAsync(degB, 0, (size_t)BG * 4, stream);
    hipMemsetAsync(curB, 0, (size_t)BG * 4, stream);
    k_count2<<<(EE + 255) / 256, 256, 0, stream>>>(e_src, e_dst, deg_e, EE);
    k_scan<<<1, 256, 0, stream>>>(deg_e, offs_e, NN);
    k_fill2<<<(EE + 255) / 256, 256, 0, stream>>>(e_src, e_dst, offs_e, cur_e, elist, EE);
    k_count1<<<(NN + 255) / 256, 256, 0, stream>>>(owner, degB, NN);
    k_scan<<<1, 256, 0, stream>>>(degB, offsB, BG);
    k_fill1<<<(NN + 255) / 256, 256, 0, stream>>>(owner, offsB, curB, nlist, NN);

    for (int p = 0; p < PP; p++) {
        short* cur = (p & 1) ? nodesB : nodesA;   // ping-pong state
        short* nxt = (p & 1) ? nodesA : nodesB;   // PP even -> final in nodesA
        // X = nodes[src] + nodes[dst]    [E,256] bf16 (nodes L2/L3-hot)
        k_xadd<<<EE / 8, 256, 0, stream>>>(cur, e_src, e_dst, bufC);
        // T = tanh([X|ef] @ [mnW|mfW]^T) [E,512] bf16 (K-concat GEMM, K=512)
        gemm_bt<1><<<EE / 128 * 4, 256, 0, stream>>>(
            bufC, ef_bf, WcombB + (size_t)p * 512 * 512, nullptr, nullptr,
            bufD, nullptr, nullptr, nullptr, nullptr,
            nullptr, nullptr, nullptr, nullptr,
            512, 256, 512, 4, 0);
        // U[n] = sum of T over incident edges (CSR gather; ml2 folded into W)
        k_edge_gather<<<NN / 4, 256, 0, stream>>>(bufD, offs_e, elist, bufI);
        // FULL GRU in one GEMM+epilogue: nodes_nxt = GRU([U|nodes_cur]@Wgru4^T
        //   + deg*cgru + bgru, nodes_cur)   (mod-4 gate interleave, EPI=5)
        gemm_bt<5><<<NN / 128 * 8, 256, 0, stream>>>(
            bufI, cur, Wgru4 + (size_t)p * 1024 * 768,
            bgru + p * 1024, cgru + p * 1024,
            nxt, nullptr, nullptr, nullptr, nullptr,
            deg_e, cur, owner, running,
            768, 512, 1024, 8, 0);
    }

    // both aggregators in ONE routed GEMM (NC=2048: cols<1024 dec, >=1024 init)
    gemm_bt<4><<<NN / 128 * 16, 256, 0, stream>>>(
        nodesA, nodesA, W4agg, dec_tb, dec_gb,
        nullptr, gpD, gpI, init_tb, init_gb,
        nullptr, nullptr, nullptr, nullptr,
        256, 256, 2048, 16, 1024);
    k_owner_reduce<<<BG, 256, 0, stream>>>(gpD, offsB, nlist, aggD);
    k_owner_reduce<<<BG, 256, 0, stream>>>(gpI, offsB, nlist, aggI);

    k_logits<<<BG, 128, 0, stream>>>(aggD, ntdW, ntdb, logitsF, outL);
    k_loss<<<1, 512, 0, stream>>>(logitsF, reft, running, outLoss);
    k_newfeat<<<BG, 256, 0, stream>>>(aggI, nte, reft, f1W, f1b, f2W, outNF);
}